// Round 8
// baseline (275.229 us; speedup 1.0000x reference)
//
#include <hip/hip_runtime.h>
#include <hip/hip_bf16.h>
#include <math.h>

#define BATCH 16384
#define NTAB 26
#define DIM 128
#define NROWS 100000

typedef short bf16x8 __attribute__((ext_vector_type(8)));
typedef float f32x4 __attribute__((ext_vector_type(4)));
typedef float f32x16 __attribute__((ext_vector_type(16)));

__device__ __forceinline__ ushort f2b(float f) {   // fp32 -> bf16 RNE
  union { float f; unsigned u; } c; c.f = f;
  unsigned r = (c.u + 0x7fffu + ((c.u >> 16) & 1u)) >> 16;
  return (ushort)r;
}
__device__ __forceinline__ float b2f(ushort u) {
  union { unsigned u; float f; } c; c.u = (unsigned)u << 16;
  return c.f;
}

__device__ __forceinline__ void gload_lds16(const void* g, void* l) {
  __builtin_amdgcn_global_load_lds(
      (const __attribute__((address_space(1))) void*)g,
      (__attribute__((address_space(3))) void*)l, 16, 0, 0);
}

// ---------------- prep: bottom layer 0 (13->512 relu) + all weight cvt, one launch ----------------
__global__ __launch_bounds__(256) void prep_kernel(
    const float* __restrict__ x, const float* __restrict__ W0,
    const float* __restrict__ b0, ushort* __restrict__ y,
    const float* __restrict__ bw1, const float* __restrict__ bw2,
    const float* __restrict__ tw0, const float* __restrict__ tw1,
    const float* __restrict__ tw2,
    ushort* __restrict__ o1, ushort* __restrict__ o2, ushort* __restrict__ o3,
    ushort* __restrict__ o4, ushort* __restrict__ o5) {
  int blk = blockIdx.x;
  if (blk < 2 * BATCH) {
    int b = blk >> 1;
    int m = ((blk & 1) << 8) | threadIdx.x;
    const float* xr = x + (size_t)b * 13;
    const float* wr = W0 + (size_t)m * 13;
    float acc = b0[m];
#pragma unroll
    for (int k = 0; k < 13; k++) acc = fmaf(xr[k], wr[k], acc);
    y[(size_t)b * 512 + m] = f2b(fmaxf(acc, 0.f));
    return;
  }
  int cb = blk - 2 * BATCH;
  int c = cb >> 11;
  int i = (cb & 2047) * 256 + threadIdx.x;
  switch (c) {
    case 0: if (i < 256 * 512) o1[i] = f2b(bw1[i]); break;
    case 1: if (i < 128 * 256) o2[i] = f2b(bw2[i]); break;
    case 2: if (i < 1024 * 512) {            // pad K 479 -> 512
      int r = i >> 9, cc = i & 511;
      o3[i] = (cc < 479) ? f2b(tw0[(size_t)r * 479 + cc]) : (ushort)0;
    } break;
    case 3: if (i < 512 * 1024) o4[i] = f2b(tw1[i]); break;
    case 4: if (i < 256 * 512) o5[i] = f2b(tw2[i]); break;
  }
}

// ---------------- fused embedding gather+pool+interaction ----------------
// Per wave = 1 batch row. Index pairs for all 26 tables are loaded FIRST via
// scalar loads (readfirstlane(b) -> provably uniform address -> s_load through
// the scalar cache, results in SGPRs). The 52 row gathers then issue with no
// idx->gather dependency chains (unroll-8 chunks bound VGPR usage).
__global__ __launch_bounds__(256) void embint_kernel(
    const float* __restrict__ tables, const int* __restrict__ lS_i,
    const ushort* __restrict__ xb, ushort* __restrict__ R) {
  __shared__ ushort Tls[4][32 * 128];          // 8 KB per wave
  const int wave = threadIdx.x >> 6, lane = threadIdx.x & 63;
  const int b = blockIdx.x * 4 + wave;
  const int bu = __builtin_amdgcn_readfirstlane(b);
  char* tl = (char*)Tls[wave];

  // all 26 index pairs, scalar path, issued before any gather
  long long pair[NTAB];
#pragma unroll
  for (int t = 0; t < NTAB; t++)
    pair[t] = *(const long long*)(lS_i + ((size_t)t << 15) + (bu << 1));

  *(uint*)(tl + lane * 4) = *(const uint*)(xb + (size_t)b * 128 + lane * 2);
#pragma unroll
  for (int r = 27; r < 32; r++)
    *(uint*)(tl + r * 256 + ((lane * 4) ^ ((r & 7) << 4))) = 0;

#pragma unroll 8
  for (int t = 0; t < NTAB; t++) {
    int i0 = (int)(pair[t] & 0xffffffffLL);
    int i1 = (int)(pair[t] >> 32);
    float2 v0 = ((const float2*)(tables + ((size_t)t * NROWS + i0) * DIM))[lane];
    float2 v1 = ((const float2*)(tables + ((size_t)t * NROWS + i1) * DIM))[lane];
    ushort2 s; s.x = f2b(v0.x + v1.x); s.y = f2b(v0.y + v1.y);
    int row = t + 1;
    *(uint*)(tl + row * 256 + ((lane * 4) ^ ((row & 7) << 4))) = *(uint*)&s;
  }
  __syncthreads();

  const int row = lane & 31;
  const int khb = (lane >> 5) * 16;
  const int swz = (row & 7) << 4;
  f32x16 z = {};
#pragma unroll
  for (int ks = 0; ks < 8; ks++) {
    bf16x8 a = *(const bf16x8*)(tl + row * 256 + ((ks * 32 + khb) ^ swz));
    z = __builtin_amdgcn_mfma_f32_32x32x16_bf16(a, a, z, 0, 0, 0);
  }

  ushort* Rb = R + (size_t)b * 512;
  *(uint*)(Rb + lane * 2) = *(const uint*)(tl + lane * 4);
  if (lane < 33) Rb[479 + lane] = 0;
  const int j = lane & 31;
  const int rb4 = (lane >> 5) * 4;
#pragma unroll
  for (int r = 0; r < 16; r++) {
    int i = (r & 3) + 8 * (r >> 2) + rb4;
    if (i <= 26 && j < i) Rb[DIM + (i * (i - 1)) / 2 + j] = f2b(z[r]);
  }
}

// ---------------- deep-pipelined bf16 GEMM: BM=256 BN=128 BK=64, 3-slot ring ----------------
#define SLOT_BYTES 49152   // A: 256x64 bf16 = 32KB, B: 128x64 bf16 = 16KB
template <int ACT>
__global__ __launch_bounds__(512, 2) void gemm256_kernel(
    const ushort* __restrict__ A, const ushort* __restrict__ W,
    const float* __restrict__ bias, ushort* __restrict__ C, int K, int ldc) {
  __shared__ char lds[3 * SLOT_BYTES];
  const int tid = threadIdx.x;
  const int lane = tid & 63, wid = tid >> 6;
  const int wm = wid >> 2, wn = wid & 3;

  // bijective XCD-chunked swizzle (m204)
  const int nwg = gridDim.x * gridDim.y;
  const int orig = blockIdx.y * gridDim.x + blockIdx.x;
  const int q = nwg >> 3, r8 = nwg & 7;
  const int xcd = orig & 7, pos = orig >> 3;
  const int swzid = (xcd < r8 ? xcd * (q + 1) : r8 * (q + 1) + (xcd - r8) * q) + pos;
  const int m0 = (swzid / gridDim.x) * 256, n0 = (swzid % gridDim.x) * 128;
  const int NK = K >> 6;

  const int srow = tid >> 3;           // staging row within 64-row group
  const int scolb = (tid & 7) << 4;    // staging col byte 0..112

  // prologue: stage K-steps 0 and 1
#pragma unroll
  for (int kt = 0; kt < 2; kt++) {
    char* As = lds + kt * SLOT_BYTES;
    char* Bs = As + 32768;
    const int k0 = kt * 64;
#pragma unroll
    for (int i = 0; i < 4; i++) {
      int row = i * 64 + srow;
      int colb = scolb ^ ((row & 7) << 4);
      gload_lds16(A + (size_t)(m0 + row) * K + k0 + (colb >> 1), As + i * 8192 + wid * 1024);
    }
#pragma unroll
    for (int i = 0; i < 2; i++) {
      int row = i * 64 + srow;
      int colb = scolb ^ ((row & 7) << 4);
      gload_lds16(W + (size_t)(n0 + row) * K + k0 + (colb >> 1), Bs + i * 8192 + wid * 1024);
    }
  }

  f32x4 acc[8][2] = {};
  const int fr = lane & 15;
  const int fkb = (lane >> 4) * 16;

  for (int kt = 0; kt < NK; kt++) {
    if (kt + 1 < NK) { asm volatile("s_waitcnt vmcnt(6)" ::: "memory"); }
    else             { asm volatile("s_waitcnt vmcnt(0)" ::: "memory"); }
    __builtin_amdgcn_sched_barrier(0);
    __builtin_amdgcn_s_barrier();
    __builtin_amdgcn_sched_barrier(0);

    const char* As = lds + (kt % 3) * SLOT_BYTES;
    const char* Bs = As + 32768;
    char* Ad = lds + ((kt + 2) % 3) * SLOT_BYTES;
    char* Bd = Ad + 32768;
    const int k2 = (kt + 2) * 64;
    const bool do_stage = (kt + 2 < NK);

#pragma unroll
    for (int kh = 0; kh < 2; kh++) {
      bf16x8 a[8], b[2];
#pragma unroll
      for (int mf = 0; mf < 8; mf++) {
        int row = wm * 128 + mf * 16 + fr;
        int colb = (kh * 64 + fkb) ^ ((row & 7) << 4);
        a[mf] = *(const bf16x8*)(As + row * 128 + colb);
      }
#pragma unroll
      for (int nf = 0; nf < 2; nf++) {
        int row = wn * 32 + nf * 16 + fr;
        int colb = (kh * 64 + fkb) ^ ((row & 7) << 4);
        b[nf] = *(const bf16x8*)(Bs + row * 128 + colb);
      }
      if (do_stage) {
#pragma unroll
        for (int i = kh * 2; i < kh * 2 + 2; i++) {
          int row = i * 64 + srow;
          int colb = scolb ^ ((row & 7) << 4);
          gload_lds16(A + (size_t)(m0 + row) * K + k2 + (colb >> 1), Ad + i * 8192 + wid * 1024);
        }
        {
          int row = kh * 64 + srow;
          int colb = scolb ^ ((row & 7) << 4);
          gload_lds16(W + (size_t)(n0 + row) * K + k2 + (colb >> 1), Bd + kh * 8192 + wid * 1024);
        }
      }
      __builtin_amdgcn_sched_barrier(0);
      __builtin_amdgcn_s_barrier();
      asm volatile("s_waitcnt lgkmcnt(0)" ::: "memory");
      __builtin_amdgcn_sched_barrier(0);
      __builtin_amdgcn_s_setprio(1);
#pragma unroll
      for (int mf = 0; mf < 8; mf++)
#pragma unroll
        for (int nf = 0; nf < 2; nf++)
          acc[mf][nf] = __builtin_amdgcn_mfma_f32_16x16x32_bf16(a[mf], b[nf], acc[mf][nf], 0, 0, 0);
      __builtin_amdgcn_s_setprio(0);
      if (kh == 0) {
        __builtin_amdgcn_sched_barrier(0);
        __builtin_amdgcn_s_barrier();
        __builtin_amdgcn_sched_barrier(0);
      }
    }
  }

  const int cr = lane & 15, rh = (lane >> 4) * 4;
#pragma unroll
  for (int nf = 0; nf < 2; nf++) {
    int n = n0 + wn * 32 + nf * 16 + cr;
    float bs = bias[n];
#pragma unroll
    for (int mf = 0; mf < 8; mf++) {
      int mb = m0 + wm * 128 + mf * 16 + rh;
#pragma unroll
      for (int r = 0; r < 4; r++) {
        float v = acc[mf][nf][r] + bs;
        if (ACT) v = fmaxf(v, 0.f);
        C[(size_t)(mb + r) * ldc + n] = f2b(v);
      }
    }
  }
}

// ---------------- 128x128 m97-structure GEMM (small layers), 4-way-swizzled LDS ----------------
template <int ACT>
__global__ __launch_bounds__(256) void gemm_bf16_kernel(
    const ushort* __restrict__ A, const ushort* __restrict__ W,
    const float* __restrict__ bias, ushort* __restrict__ C, int K, int ldc) {
  __shared__ ushort As[128 * 32];
  __shared__ ushort Bs[128 * 32];
  const int tid = threadIdx.x;
  const int lane = tid & 63, wave = tid >> 6;
  const int m0 = blockIdx.y * 128, n0 = blockIdx.x * 128;
  const int wr = wave >> 1, wc = wave & 1;

  const int srow = lane >> 2;
  const int scolb = ((lane & 3) << 4) ^ ((srow & 3) << 4);   // pre-swizzled src
  const ushort* Ag = A + (size_t)(m0 + wave * 16 + srow) * K + (scolb >> 1);
  const ushort* Wg = W + (size_t)(n0 + wave * 16 + srow) * K + (scolb >> 1);
  ushort* AsW = &As[(wave * 16) * 32];
  ushort* BsW = &Bs[(wave * 16) * 32];

  f32x4 acc[4][4] = {};
  const int fr = lane & 15;
  const int fkb = (lane >> 4) * 16;
  const int fswz = (fr & 3) << 4;

  for (int k0 = 0; k0 < K; k0 += 32) {
    gload_lds16(Ag + k0, AsW);
    gload_lds16(Ag + (size_t)64 * K + k0, AsW + 64 * 32);
    gload_lds16(Wg + k0, BsW);
    gload_lds16(Wg + (size_t)64 * K + k0, BsW + 64 * 32);
    __syncthreads();
    bf16x8 a[4], b[4];
#pragma unroll
    for (int i = 0; i < 4; i++) {
      a[i] = *(const bf16x8*)((const char*)As + (wr * 64 + i * 16 + fr) * 64 + (fkb ^ fswz));
      b[i] = *(const bf16x8*)((const char*)Bs + (wc * 64 + i * 16 + fr) * 64 + (fkb ^ fswz));
    }
#pragma unroll
    for (int i = 0; i < 4; i++)
#pragma unroll
      for (int j = 0; j < 4; j++)
        acc[i][j] = __builtin_amdgcn_mfma_f32_16x16x32_bf16(a[i], b[j], acc[i][j], 0, 0, 0);
    __syncthreads();
  }

  const int col_l = lane & 15, row_h = (lane >> 4) * 4;
#pragma unroll
  for (int j = 0; j < 4; j++) {
    int n = n0 + wc * 64 + j * 16 + col_l;
    float bs = bias[n];
#pragma unroll
    for (int i = 0; i < 4; i++) {
      int mbase = m0 + wr * 64 + i * 16 + row_h;
#pragma unroll
      for (int r = 0; r < 4; r++) {
        float v = acc[i][j][r] + bs;
        if (ACT) v = fmaxf(v, 0.f);
        C[(size_t)(mbase + r) * ldc + n] = f2b(v);
      }
    }
  }
}

// ---------------- fused t2 (512->256 relu) + final (256->1 sigmoid) ----------------
__global__ __launch_bounds__(256) void t2final_kernel(
    const ushort* __restrict__ A, const ushort* __restrict__ W,
    const float* __restrict__ bias, const float* __restrict__ w3,
    const float* __restrict__ b3, float* __restrict__ out) {
  __shared__ char smem[64 * 264 * 2];        // 33.8 KB; As/Bs overlay in front
  ushort* As = (ushort*)smem;                // 64 x 32 (4 KB)
  ushort* Bs = (ushort*)(smem + 4096);       // 256 x 32 (16 KB)
  ushort* Ct = (ushort*)smem;                // 64 x 264 after compute
  const int tid = threadIdx.x;
  const int lane = tid & 63, wave = tid >> 6;
  const int m0 = blockIdx.x * 64;

  const int srow = lane >> 2;
  const int scolb = ((lane & 3) << 4) ^ ((srow & 3) << 4);
  const ushort* Ag = A + (size_t)(m0 + wave * 16 + srow) * 512 + (scolb >> 1);
  const ushort* Wg = W + (size_t)(wave * 16 + srow) * 512 + (scolb >> 1);

  f32x4 acc[4][4] = {};
  const int fr = lane & 15;
  const int fkb = (lane >> 4) * 16;
  const int fswz = (fr & 3) << 4;

  for (int k0 = 0; k0 < 512; k0 += 32) {
    gload_lds16(Ag + k0, (char*)As + wave * 1024);
#pragma unroll
    for (int i = 0; i < 4; i++)
      gload_lds16(Wg + (size_t)(i * 64) * 512 + k0, (char*)Bs + i * 4096 + wave * 1024);
    __syncthreads();
    bf16x8 a[4], b[4];
#pragma unroll
    for (int i = 0; i < 4; i++) {
      a[i] = *(const bf16x8*)((const char*)As + (i * 16 + fr) * 64 + (fkb ^ fswz));
      b[i] = *(const bf16x8*)((const char*)Bs + (wave * 64 + i * 16 + fr) * 64 + (fkb ^ fswz));
    }
#pragma unroll
    for (int i = 0; i < 4; i++)
#pragma unroll
      for (int j = 0; j < 4; j++)
        acc[i][j] = __builtin_amdgcn_mfma_f32_16x16x32_bf16(a[i], b[j], acc[i][j], 0, 0, 0);
    __syncthreads();
  }

  const int col_l = lane & 15, row_h = (lane >> 4) * 4;
#pragma unroll
  for (int j = 0; j < 4; j++) {
    int n = wave * 64 + j * 16 + col_l;
    float bs = bias[n];
#pragma unroll
    for (int i = 0; i < 4; i++) {
      int mb = i * 16 + row_h;
#pragma unroll
      for (int r = 0; r < 4; r++)
        Ct[(size_t)(mb + r) * 264 + n] = f2b(fmaxf(acc[i][j][r] + bs, 0.f));
    }
  }
  __syncthreads();

  const float4 wv = ((const float4*)w3)[lane];
  const float bf = b3[0];
  for (int rr = 0; rr < 16; rr++) {
    int row = wave * 16 + rr;
    ushort4 a4 = *(const ushort4*)&Ct[(size_t)row * 264 + lane * 4];
    float s = b2f(a4.x) * wv.x + b2f(a4.y) * wv.y + b2f(a4.z) * wv.z + b2f(a4.w) * wv.w;
#pragma unroll
    for (int off = 32; off >= 1; off >>= 1) s += __shfl_xor(s, off);
    if (lane == 0) out[m0 + row] = 1.f / (1.f + expf(-(s + bf)));
  }
}

extern "C" void kernel_launch(void* const* d_in, const int* in_sizes, int n_in,
                              void* d_out, int out_size, void* d_ws, size_t ws_size,
                              hipStream_t stream) {
  const float* dense_x = (const float*)d_in[0];
  const int* lS_i = (const int*)d_in[2];
  const float* emb = (const float*)d_in[3];
  const float* bw0 = (const float*)d_in[4];
  const float* bb0 = (const float*)d_in[5];
  const float* bw1 = (const float*)d_in[6];
  const float* bb1 = (const float*)d_in[7];
  const float* bw2 = (const float*)d_in[8];
  const float* bb2 = (const float*)d_in[9];
  const float* tw0 = (const float*)d_in[10];
  const float* tb0 = (const float*)d_in[11];
  const float* tw1 = (const float*)d_in[12];
  const float* tb1 = (const float*)d_in[13];
  const float* tw2 = (const float*)d_in[14];
  const float* tb2 = (const float*)d_in[15];
  const float* tw3 = (const float*)d_in[16];
  const float* tb3 = (const float*)d_in[17];
  float* out = (float*)d_out;

  // workspace layout (bf16)
  char* w = (char*)d_ws;
  ushort* xb  = (ushort*)w; w += (size_t)BATCH * 128 * 2;
  ushort* x1  = (ushort*)w; w += (size_t)BATCH * 512 * 2;
  ushort* x2  = (ushort*)w; w += (size_t)BATCH * 256 * 2;
  ushort* R   = (ushort*)w; w += (size_t)BATCH * 512 * 2;
  ushort* t1  = (ushort*)w; w += (size_t)BATCH * 1024 * 2;
  ushort* wb1 = (ushort*)w; w += 256 * 512 * 2;
  ushort* wb2 = (ushort*)w; w += 128 * 256 * 2;
  ushort* wt0 = (ushort*)w; w += 1024 * 512 * 2;
  ushort* wt1 = (ushort*)w; w += 512 * 1024 * 2;
  ushort* wt2 = (ushort*)w; w += 256 * 512 * 2;
  ushort* t2 = x1;   // reuse (B x 512)

  // prep: bot0 + all weight conversions (one launch)
  prep_kernel<<<2 * BATCH + 5 * 2048, 256, 0, stream>>>(
      dense_x, bw0, bb0, x1, bw1, bw2, tw0, tw1, tw2, wb1, wb2, wt0, wt1, wt2);

  // bottom MLP -> xb (packed B x 128)
  gemm_bf16_kernel<1><<<dim3(2, BATCH / 128), 256, 0, stream>>>(x1, wb1, bb1, x2, 512, 256);
  gemm_bf16_kernel<1><<<dim3(1, BATCH / 128), 256, 0, stream>>>(x2, wb2, bb2, xb, 256, 128);

  // fused embeddings + interaction -> R = [x | tril(Z) | 0pad]
  embint_kernel<<<BATCH / 4, 256, 0, stream>>>(emb, lS_i, xb, R);

  // top MLP
  gemm256_kernel<1><<<dim3(1024 / 128, BATCH / 256), 512, 0, stream>>>(R,  wt0, tb0, t1, 512, 1024);
  gemm256_kernel<1><<<dim3(512 / 128,  BATCH / 256), 512, 0, stream>>>(t1, wt1, tb1, t2, 1024, 512);
  t2final_kernel<<<BATCH / 64, 256, 0, stream>>>(t2, wt2, tb2, tw3, tb3, out);
}

// Round 9
// 218.214 us; speedup vs baseline: 1.2613x; 1.2613x over previous
//
#include <hip/hip_runtime.h>
#include <hip/hip_bf16.h>
#include <math.h>

#define BATCH 16384
#define NTAB 26
#define DIM 128
#define NROWS 100000

typedef short bf16x8 __attribute__((ext_vector_type(8)));
typedef float f32x4 __attribute__((ext_vector_type(4)));
typedef float f32x16 __attribute__((ext_vector_type(16)));

__device__ __forceinline__ ushort f2b(float f) {   // fp32 -> bf16 RNE
  union { float f; unsigned u; } c; c.f = f;
  unsigned r = (c.u + 0x7fffu + ((c.u >> 16) & 1u)) >> 16;
  return (ushort)r;
}
__device__ __forceinline__ float b2f(ushort u) {
  union { unsigned u; float f; } c; c.u = (unsigned)u << 16;
  return c.f;
}

__device__ __forceinline__ void gload_lds16(const void* g, void* l) {
  __builtin_amdgcn_global_load_lds(
      (const __attribute__((address_space(1))) void*)g,
      (__attribute__((address_space(3))) void*)l, 16, 0, 0);
}

// ---------------- prep: bottom layer 0 (13->512 relu) + all weight cvt, one launch ----------------
__global__ __launch_bounds__(256) void prep_kernel(
    const float* __restrict__ x, const float* __restrict__ W0,
    const float* __restrict__ b0, ushort* __restrict__ y,
    const float* __restrict__ bw1, const float* __restrict__ bw2,
    const float* __restrict__ tw0, const float* __restrict__ tw1,
    const float* __restrict__ tw2,
    ushort* __restrict__ o1, ushort* __restrict__ o2, ushort* __restrict__ o3,
    ushort* __restrict__ o4, ushort* __restrict__ o5) {
  int blk = blockIdx.x;
  if (blk < 2 * BATCH) {
    int b = blk >> 1;
    int m = ((blk & 1) << 8) | threadIdx.x;
    const float* xr = x + (size_t)b * 13;
    const float* wr = W0 + (size_t)m * 13;
    float acc = b0[m];
#pragma unroll
    for (int k = 0; k < 13; k++) acc = fmaf(xr[k], wr[k], acc);
    y[(size_t)b * 512 + m] = f2b(fmaxf(acc, 0.f));
    return;
  }
  int cb = blk - 2 * BATCH;
  int c = cb >> 11;
  int i = (cb & 2047) * 256 + threadIdx.x;
  switch (c) {
    case 0: if (i < 256 * 512) o1[i] = f2b(bw1[i]); break;
    case 1: if (i < 128 * 256) o2[i] = f2b(bw2[i]); break;
    case 2: if (i < 1024 * 512) {            // pad K 479 -> 512
      int r = i >> 9, cc = i & 511;
      o3[i] = (cc < 479) ? f2b(tw0[(size_t)r * 479 + cc]) : (ushort)0;
    } break;
    case 3: if (i < 512 * 1024) o4[i] = f2b(tw1[i]); break;
    case 4: if (i < 256 * 512) o5[i] = f2b(tw2[i]); break;
  }
}

// ---------------- fused embedding gather+pool+interaction (round-6 form) ----------------
__global__ __launch_bounds__(256) void embint_kernel(
    const float* __restrict__ tables, const int* __restrict__ lS_i,
    const ushort* __restrict__ xb, ushort* __restrict__ R) {
  __shared__ ushort Tls[4][32 * 128];          // 8 KB per wave
  const int wave = threadIdx.x >> 6, lane = threadIdx.x & 63;
  const int b = blockIdx.x * 4 + wave;
  char* tl = (char*)Tls[wave];

  *(uint*)(tl + lane * 4) = *(const uint*)(xb + (size_t)b * 128 + lane * 2);
#pragma unroll
  for (int r = 27; r < 32; r++)
    *(uint*)(tl + r * 256 + ((lane * 4) ^ ((r & 7) << 4))) = 0;
#pragma unroll 8
  for (int t = 0; t < NTAB; t++) {
    const int* idx = lS_i + ((size_t)t << 15) + (b << 1);
    int i0 = idx[0], i1 = idx[1];
    float2 v0 = ((const float2*)(tables + ((size_t)t * NROWS + i0) * DIM))[lane];
    float2 v1 = ((const float2*)(tables + ((size_t)t * NROWS + i1) * DIM))[lane];
    ushort2 s; s.x = f2b(v0.x + v1.x); s.y = f2b(v0.y + v1.y);
    int row = t + 1;
    *(uint*)(tl + row * 256 + ((lane * 4) ^ ((row & 7) << 4))) = *(uint*)&s;
  }
  __syncthreads();

  const int row = lane & 31;
  const int khb = (lane >> 5) * 16;
  const int swz = (row & 7) << 4;
  f32x16 z = {};
#pragma unroll
  for (int ks = 0; ks < 8; ks++) {
    bf16x8 a = *(const bf16x8*)(tl + row * 256 + ((ks * 32 + khb) ^ swz));
    z = __builtin_amdgcn_mfma_f32_32x32x16_bf16(a, a, z, 0, 0, 0);
  }

  ushort* Rb = R + (size_t)b * 512;
  *(uint*)(Rb + lane * 2) = *(const uint*)(tl + lane * 4);
  if (lane < 33) Rb[479 + lane] = 0;
  const int j = lane & 31;
  const int rb4 = (lane >> 5) * 4;
#pragma unroll
  for (int r = 0; r < 16; r++) {
    int i = (r & 3) + 8 * (r >> 2) + rb4;
    if (i <= 26 && j < i) Rb[DIM + (i * (i - 1)) / 2 + j] = f2b(z[r]);
  }
}

// ---------------- deep-pipelined bf16 GEMM: BM=256 BN=128 BK=64, 3-slot ring ----------------
#define SLOT_BYTES 49152   // A: 256x64 bf16 = 32KB, B: 128x64 bf16 = 16KB
template <int ACT>
__global__ __launch_bounds__(512, 2) void gemm256_kernel(
    const ushort* __restrict__ A, const ushort* __restrict__ W,
    const float* __restrict__ bias, ushort* __restrict__ C, int K, int ldc) {
  __shared__ char lds[3 * SLOT_BYTES];
  const int tid = threadIdx.x;
  const int lane = tid & 63, wid = tid >> 6;
  const int wm = wid >> 2, wn = wid & 3;

  // bijective XCD-chunked swizzle (m204)
  const int nwg = gridDim.x * gridDim.y;
  const int orig = blockIdx.y * gridDim.x + blockIdx.x;
  const int q = nwg >> 3, r8 = nwg & 7;
  const int xcd = orig & 7, pos = orig >> 3;
  const int swzid = (xcd < r8 ? xcd * (q + 1) : r8 * (q + 1) + (xcd - r8) * q) + pos;
  const int m0 = (swzid / gridDim.x) * 256, n0 = (swzid % gridDim.x) * 128;
  const int NK = K >> 6;

  const int srow = tid >> 3;           // staging row within 64-row group
  const int scolb = (tid & 7) << 4;    // staging col byte 0..112

  // prologue: stage K-steps 0 and 1
#pragma unroll
  for (int kt = 0; kt < 2; kt++) {
    char* As = lds + kt * SLOT_BYTES;
    char* Bs = As + 32768;
    const int k0 = kt * 64;
#pragma unroll
    for (int i = 0; i < 4; i++) {
      int row = i * 64 + srow;
      int colb = scolb ^ ((row & 7) << 4);
      gload_lds16(A + (size_t)(m0 + row) * K + k0 + (colb >> 1), As + i * 8192 + wid * 1024);
    }
#pragma unroll
    for (int i = 0; i < 2; i++) {
      int row = i * 64 + srow;
      int colb = scolb ^ ((row & 7) << 4);
      gload_lds16(W + (size_t)(n0 + row) * K + k0 + (colb >> 1), Bs + i * 8192 + wid * 1024);
    }
  }

  f32x4 acc[8][2] = {};
  const int fr = lane & 15;
  const int fkb = (lane >> 4) * 16;

  for (int kt = 0; kt < NK; kt++) {
    if (kt + 1 < NK) { asm volatile("s_waitcnt vmcnt(6)" ::: "memory"); }
    else             { asm volatile("s_waitcnt vmcnt(0)" ::: "memory"); }
    __builtin_amdgcn_sched_barrier(0);
    __builtin_amdgcn_s_barrier();
    __builtin_amdgcn_sched_barrier(0);

    const char* As = lds + (kt % 3) * SLOT_BYTES;
    const char* Bs = As + 32768;
    char* Ad = lds + ((kt + 2) % 3) * SLOT_BYTES;
    char* Bd = Ad + 32768;
    const int k2 = (kt + 2) * 64;
    const bool do_stage = (kt + 2 < NK);

#pragma unroll
    for (int kh = 0; kh < 2; kh++) {
      bf16x8 a[8], b[2];
#pragma unroll
      for (int mf = 0; mf < 8; mf++) {
        int row = wm * 128 + mf * 16 + fr;
        int colb = (kh * 64 + fkb) ^ ((row & 7) << 4);
        a[mf] = *(const bf16x8*)(As + row * 128 + colb);
      }
#pragma unroll
      for (int nf = 0; nf < 2; nf++) {
        int row = wn * 32 + nf * 16 + fr;
        int colb = (kh * 64 + fkb) ^ ((row & 7) << 4);
        b[nf] = *(const bf16x8*)(Bs + row * 128 + colb);
      }
      if (do_stage) {
#pragma unroll
        for (int i = kh * 2; i < kh * 2 + 2; i++) {
          int row = i * 64 + srow;
          int colb = scolb ^ ((row & 7) << 4);
          gload_lds16(A + (size_t)(m0 + row) * K + k2 + (colb >> 1), Ad + i * 8192 + wid * 1024);
        }
        {
          int row = kh * 64 + srow;
          int colb = scolb ^ ((row & 7) << 4);
          gload_lds16(W + (size_t)(n0 + row) * K + k2 + (colb >> 1), Bd + kh * 8192 + wid * 1024);
        }
      }
      __builtin_amdgcn_sched_barrier(0);
      __builtin_amdgcn_s_barrier();
      asm volatile("s_waitcnt lgkmcnt(0)" ::: "memory");
      __builtin_amdgcn_sched_barrier(0);
      __builtin_amdgcn_s_setprio(1);
#pragma unroll
      for (int mf = 0; mf < 8; mf++)
#pragma unroll
        for (int nf = 0; nf < 2; nf++)
          acc[mf][nf] = __builtin_amdgcn_mfma_f32_16x16x32_bf16(a[mf], b[nf], acc[mf][nf], 0, 0, 0);
      __builtin_amdgcn_s_setprio(0);
      if (kh == 0) {
        __builtin_amdgcn_sched_barrier(0);
        __builtin_amdgcn_s_barrier();
        __builtin_amdgcn_sched_barrier(0);
      }
    }
  }

  const int cr = lane & 15, rh = (lane >> 4) * 4;
#pragma unroll
  for (int nf = 0; nf < 2; nf++) {
    int n = n0 + wn * 32 + nf * 16 + cr;
    float bs = bias[n];
#pragma unroll
    for (int mf = 0; mf < 8; mf++) {
      int mb = m0 + wm * 128 + mf * 16 + rh;
#pragma unroll
      for (int r = 0; r < 4; r++) {
        float v = acc[mf][nf][r] + bs;
        if (ACT) v = fmaxf(v, 0.f);
        C[(size_t)(mb + r) * ldc + n] = f2b(v);
      }
    }
  }
}

// ---------------- 128x128 m97-structure GEMM (small layers), 4-way-swizzled LDS ----------------
template <int ACT>
__global__ __launch_bounds__(256) void gemm_bf16_kernel(
    const ushort* __restrict__ A, const ushort* __restrict__ W,
    const float* __restrict__ bias, ushort* __restrict__ C, int K, int ldc) {
  __shared__ ushort As[128 * 32];
  __shared__ ushort Bs[128 * 32];
  const int tid = threadIdx.x;
  const int lane = tid & 63, wave = tid >> 6;
  const int m0 = blockIdx.y * 128, n0 = blockIdx.x * 128;
  const int wr = wave >> 1, wc = wave & 1;

  const int srow = lane >> 2;
  const int scolb = ((lane & 3) << 4) ^ ((srow & 3) << 4);   // pre-swizzled src
  const ushort* Ag = A + (size_t)(m0 + wave * 16 + srow) * K + (scolb >> 1);
  const ushort* Wg = W + (size_t)(n0 + wave * 16 + srow) * K + (scolb >> 1);
  ushort* AsW = &As[(wave * 16) * 32];
  ushort* BsW = &Bs[(wave * 16) * 32];

  f32x4 acc[4][4] = {};
  const int fr = lane & 15;
  const int fkb = (lane >> 4) * 16;
  const int fswz = (fr & 3) << 4;

  for (int k0 = 0; k0 < K; k0 += 32) {
    gload_lds16(Ag + k0, AsW);
    gload_lds16(Ag + (size_t)64 * K + k0, AsW + 64 * 32);
    gload_lds16(Wg + k0, BsW);
    gload_lds16(Wg + (size_t)64 * K + k0, BsW + 64 * 32);
    __syncthreads();
    bf16x8 a[4], b[4];
#pragma unroll
    for (int i = 0; i < 4; i++) {
      a[i] = *(const bf16x8*)((const char*)As + (wr * 64 + i * 16 + fr) * 64 + (fkb ^ fswz));
      b[i] = *(const bf16x8*)((const char*)Bs + (wc * 64 + i * 16 + fr) * 64 + (fkb ^ fswz));
    }
#pragma unroll
    for (int i = 0; i < 4; i++)
#pragma unroll
      for (int j = 0; j < 4; j++)
        acc[i][j] = __builtin_amdgcn_mfma_f32_16x16x32_bf16(a[i], b[j], acc[i][j], 0, 0, 0);
    __syncthreads();
  }

  const int col_l = lane & 15, row_h = (lane >> 4) * 4;
#pragma unroll
  for (int j = 0; j < 4; j++) {
    int n = n0 + wc * 64 + j * 16 + col_l;
    float bs = bias[n];
#pragma unroll
    for (int i = 0; i < 4; i++) {
      int mbase = m0 + wr * 64 + i * 16 + row_h;
#pragma unroll
      for (int r = 0; r < 4; r++) {
        float v = acc[i][j][r] + bs;
        if (ACT) v = fmaxf(v, 0.f);
        C[(size_t)(mbase + r) * ldc + n] = f2b(v);
      }
    }
  }
}

// ---------------- fused t2 (512->256 relu) + final (256->1 sigmoid) ----------------
__global__ __launch_bounds__(256) void t2final_kernel(
    const ushort* __restrict__ A, const ushort* __restrict__ W,
    const float* __restrict__ bias, const float* __restrict__ w3,
    const float* __restrict__ b3, float* __restrict__ out) {
  __shared__ char smem[64 * 264 * 2];        // 33.8 KB; As/Bs overlay in front
  ushort* As = (ushort*)smem;                // 64 x 32 (4 KB)
  ushort* Bs = (ushort*)(smem + 4096);       // 256 x 32 (16 KB)
  ushort* Ct = (ushort*)smem;                // 64 x 264 after compute
  const int tid = threadIdx.x;
  const int lane = tid & 63, wave = tid >> 6;
  const int m0 = blockIdx.x * 64;

  const int srow = lane >> 2;
  const int scolb = ((lane & 3) << 4) ^ ((srow & 3) << 4);
  const ushort* Ag = A + (size_t)(m0 + wave * 16 + srow) * 512 + (scolb >> 1);
  const ushort* Wg = W + (size_t)(wave * 16 + srow) * 512 + (scolb >> 1);

  f32x4 acc[4][4] = {};
  const int fr = lane & 15;
  const int fkb = (lane >> 4) * 16;
  const int fswz = (fr & 3) << 4;

  for (int k0 = 0; k0 < 512; k0 += 32) {
    gload_lds16(Ag + k0, (char*)As + wave * 1024);
#pragma unroll
    for (int i = 0; i < 4; i++)
      gload_lds16(Wg + (size_t)(i * 64) * 512 + k0, (char*)Bs + i * 4096 + wave * 1024);
    __syncthreads();
    bf16x8 a[4], b[4];
#pragma unroll
    for (int i = 0; i < 4; i++) {
      a[i] = *(const bf16x8*)((const char*)As + (i * 16 + fr) * 64 + (fkb ^ fswz));
      b[i] = *(const bf16x8*)((const char*)Bs + (wave * 64 + i * 16 + fr) * 64 + (fkb ^ fswz));
    }
#pragma unroll
    for (int i = 0; i < 4; i++)
#pragma unroll
      for (int j = 0; j < 4; j++)
        acc[i][j] = __builtin_amdgcn_mfma_f32_16x16x32_bf16(a[i], b[j], acc[i][j], 0, 0, 0);
    __syncthreads();
  }

  const int col_l = lane & 15, row_h = (lane >> 4) * 4;
#pragma unroll
  for (int j = 0; j < 4; j++) {
    int n = wave * 64 + j * 16 + col_l;
    float bs = bias[n];
#pragma unroll
    for (int i = 0; i < 4; i++) {
      int mb = i * 16 + row_h;
#pragma unroll
      for (int r = 0; r < 4; r++)
        Ct[(size_t)(mb + r) * 264 + n] = f2b(fmaxf(acc[i][j][r] + bs, 0.f));
    }
  }
  __syncthreads();

  const float4 wv = ((const float4*)w3)[lane];
  const float bf = b3[0];
  for (int rr = 0; rr < 16; rr++) {
    int row = wave * 16 + rr;
    ushort4 a4 = *(const ushort4*)&Ct[(size_t)row * 264 + lane * 4];
    float s = b2f(a4.x) * wv.x + b2f(a4.y) * wv.y + b2f(a4.z) * wv.z + b2f(a4.w) * wv.w;
#pragma unroll
    for (int off = 32; off >= 1; off >>= 1) s += __shfl_xor(s, off);
    if (lane == 0) out[m0 + row] = 1.f / (1.f + expf(-(s + bf)));
  }
}

extern "C" void kernel_launch(void* const* d_in, const int* in_sizes, int n_in,
                              void* d_out, int out_size, void* d_ws, size_t ws_size,
                              hipStream_t stream) {
  const float* dense_x = (const float*)d_in[0];
  const int* lS_i = (const int*)d_in[2];
  const float* emb = (const float*)d_in[3];
  const float* bw0 = (const float*)d_in[4];
  const float* bb0 = (const float*)d_in[5];
  const float* bw1 = (const float*)d_in[6];
  const float* bb1 = (const float*)d_in[7];
  const float* bw2 = (const float*)d_in[8];
  const float* bb2 = (const float*)d_in[9];
  const float* tw0 = (const float*)d_in[10];
  const float* tb0 = (const float*)d_in[11];
  const float* tw1 = (const float*)d_in[12];
  const float* tb1 = (const float*)d_in[13];
  const float* tw2 = (const float*)d_in[14];
  const float* tb2 = (const float*)d_in[15];
  const float* tw3 = (const float*)d_in[16];
  const float* tb3 = (const float*)d_in[17];
  float* out = (float*)d_out;

  // workspace layout (bf16)
  char* w = (char*)d_ws;
  ushort* xb  = (ushort*)w; w += (size_t)BATCH * 128 * 2;
  ushort* x1  = (ushort*)w; w += (size_t)BATCH * 512 * 2;
  ushort* x2  = (ushort*)w; w += (size_t)BATCH * 256 * 2;
  ushort* R   = (ushort*)w; w += (size_t)BATCH * 512 * 2;
  ushort* t1  = (ushort*)w; w += (size_t)BATCH * 1024 * 2;
  ushort* wb1 = (ushort*)w; w += 256 * 512 * 2;
  ushort* wb2 = (ushort*)w; w += 128 * 256 * 2;
  ushort* wt0 = (ushort*)w; w += 1024 * 512 * 2;
  ushort* wt1 = (ushort*)w; w += 512 * 1024 * 2;
  ushort* wt2 = (ushort*)w; w += 256 * 512 * 2;
  ushort* t2 = x1;   // reuse (B x 512)

  // prep: bot0 + all weight conversions (one launch)
  prep_kernel<<<2 * BATCH + 5 * 2048, 256, 0, stream>>>(
      dense_x, bw0, bb0, x1, bw1, bw2, tw0, tw1, tw2, wb1, wb2, wt0, wt1, wt2);

  // bottom MLP -> xb (packed B x 128)
  gemm_bf16_kernel<1><<<dim3(2, BATCH / 128), 256, 0, stream>>>(x1, wb1, bb1, x2, 512, 256);
  gemm_bf16_kernel<1><<<dim3(1, BATCH / 128), 256, 0, stream>>>(x2, wb2, bb2, xb, 256, 128);

  // fused embeddings + interaction -> R = [x | tril(Z) | 0pad]
  embint_kernel<<<BATCH / 4, 256, 0, stream>>>(emb, lS_i, xb, R);

  // top MLP
  gemm256_kernel<1><<<dim3(1024 / 128, BATCH / 256), 512, 0, stream>>>(R,  wt0, tb0, t1, 512, 1024);
  gemm256_kernel<1><<<dim3(512 / 128,  BATCH / 256), 512, 0, stream>>>(t1, wt1, tb1, t2, 1024, 512);
  t2final_kernel<<<BATCH / 64, 256, 0, stream>>>(t2, wt2, tb2, tw3, tb3, out);
}

// Round 10
// 204.764 us; speedup vs baseline: 1.3441x; 1.0657x over previous
//
#include <hip/hip_runtime.h>
#include <hip/hip_bf16.h>
#include <math.h>

#define BATCH 16384
#define NTAB 26
#define DIM 128
#define NROWS 100000

typedef short bf16x8 __attribute__((ext_vector_type(8)));
typedef float f32x4 __attribute__((ext_vector_type(4)));
typedef float f32x16 __attribute__((ext_vector_type(16)));

__device__ __forceinline__ ushort f2b(float f) {   // fp32 -> bf16 RNE
  union { float f; unsigned u; } c; c.f = f;
  unsigned r = (c.u + 0x7fffu + ((c.u >> 16) & 1u)) >> 16;
  return (ushort)r;
}
__device__ __forceinline__ float b2f(ushort u) {
  union { unsigned u; float f; } c; c.u = (unsigned)u << 16;
  return c.f;
}

__device__ __forceinline__ void gload_lds16(const void* g, void* l) {
  __builtin_amdgcn_global_load_lds(
      (const __attribute__((address_space(1))) void*)g,
      (__attribute__((address_space(3))) void*)l, 16, 0, 0);
}

// ---------------- prep: bottom layer 0 (13->512 relu) + all weight cvt, one launch ----------------
// NOTE: wb2 (case 1) is stored PRE-SWIZZLED: byte ^= ((row&7)<<4) within each 512B row,
// so bmlp can stage it linearly via global_load_lds and read with the same XOR (rule 21).
__global__ __launch_bounds__(256) void prep_kernel(
    const float* __restrict__ x, const float* __restrict__ W0,
    const float* __restrict__ b0, ushort* __restrict__ y,
    const float* __restrict__ bw1, const float* __restrict__ bw2,
    const float* __restrict__ tw0, const float* __restrict__ tw1,
    const float* __restrict__ tw2,
    ushort* __restrict__ o1, ushort* __restrict__ o2, ushort* __restrict__ o3,
    ushort* __restrict__ o4, ushort* __restrict__ o5) {
  int blk = blockIdx.x;
  if (blk < 2 * BATCH) {
    int b = blk >> 1;
    int m = ((blk & 1) << 8) | threadIdx.x;
    const float* xr = x + (size_t)b * 13;
    const float* wr = W0 + (size_t)m * 13;
    float acc = b0[m];
#pragma unroll
    for (int k = 0; k < 13; k++) acc = fmaf(xr[k], wr[k], acc);
    y[(size_t)b * 512 + m] = f2b(fmaxf(acc, 0.f));
    return;
  }
  int cb = blk - 2 * BATCH;
  int c = cb >> 11;
  int i = (cb & 2047) * 256 + threadIdx.x;
  switch (c) {
    case 0: if (i < 256 * 512) o1[i] = f2b(bw1[i]); break;
    case 1: if (i < 128 * 256) {             // pre-swizzled store
      int r = i >> 8, cc = i & 255;
      int db = (((cc << 1) ^ ((r & 7) << 4)) >> 1);
      o2[r * 256 + db] = f2b(bw2[i]);
    } break;
    case 2: if (i < 1024 * 512) {            // pad K 479 -> 512
      int r = i >> 9, cc = i & 511;
      o3[i] = (cc < 479) ? f2b(tw0[(size_t)r * 479 + cc]) : (ushort)0;
    } break;
    case 3: if (i < 512 * 1024) o4[i] = f2b(tw1[i]); break;
    case 4: if (i < 256 * 512) o5[i] = f2b(tw2[i]); break;
  }
}

// ---------------- fused embedding gather+pool+interaction (round-6 form) ----------------
__global__ __launch_bounds__(256) void embint_kernel(
    const float* __restrict__ tables, const int* __restrict__ lS_i,
    const ushort* __restrict__ xb, ushort* __restrict__ R) {
  __shared__ ushort Tls[4][32 * 128];          // 8 KB per wave
  const int wave = threadIdx.x >> 6, lane = threadIdx.x & 63;
  const int b = blockIdx.x * 4 + wave;
  char* tl = (char*)Tls[wave];

  *(uint*)(tl + lane * 4) = *(const uint*)(xb + (size_t)b * 128 + lane * 2);
#pragma unroll
  for (int r = 27; r < 32; r++)
    *(uint*)(tl + r * 256 + ((lane * 4) ^ ((r & 7) << 4))) = 0;
#pragma unroll 8
  for (int t = 0; t < NTAB; t++) {
    const int* idx = lS_i + ((size_t)t << 15) + (b << 1);
    int i0 = idx[0], i1 = idx[1];
    float2 v0 = ((const float2*)(tables + ((size_t)t * NROWS + i0) * DIM))[lane];
    float2 v1 = ((const float2*)(tables + ((size_t)t * NROWS + i1) * DIM))[lane];
    ushort2 s; s.x = f2b(v0.x + v1.x); s.y = f2b(v0.y + v1.y);
    int row = t + 1;
    *(uint*)(tl + row * 256 + ((lane * 4) ^ ((row & 7) << 4))) = *(uint*)&s;
  }
  __syncthreads();

  const int row = lane & 31;
  const int khb = (lane >> 5) * 16;
  const int swz = (row & 7) << 4;
  f32x16 z = {};
#pragma unroll
  for (int ks = 0; ks < 8; ks++) {
    bf16x8 a = *(const bf16x8*)(tl + row * 256 + ((ks * 32 + khb) ^ swz));
    z = __builtin_amdgcn_mfma_f32_32x32x16_bf16(a, a, z, 0, 0, 0);
  }

  ushort* Rb = R + (size_t)b * 512;
  *(uint*)(Rb + lane * 2) = *(const uint*)(tl + lane * 4);
  if (lane < 33) Rb[479 + lane] = 0;
  const int j = lane & 31;
  const int rb4 = (lane >> 5) * 4;
#pragma unroll
  for (int r = 0; r < 16; r++) {
    int i = (r & 3) + 8 * (r >> 2) + rb4;
    if (i <= 26 && j < i) Rb[DIM + (i * (i - 1)) / 2 + j] = f2b(z[r]);
  }
}

// ---------------- fused bottom MLP: 512 -> 256 (relu) -> 128 (relu), one kernel ----------------
// 64 batch rows/block, 256 threads = 4 waves (1x4 over cols).
// Layer 1: K=512, 3-slot LDS ring (As 4KB + W1s 16KB per slot), counted vmcnt(5),
//          one s_barrier per K-step (gemm256 discipline). Wave-tile 64x64, acc1 4x4.
// C1 kept in LDS [64][260] bf16 (stride 260 rotates banks). W2 (128x256) staged once
// at kernel start from PRE-SWIZZLED global (prep case 1). Layer 2: K=256, LDS-resident.
#define BMLP_SLOT 20480
__global__ __launch_bounds__(256) void bmlp_kernel(
    const ushort* __restrict__ A, const ushort* __restrict__ W1,
    const float* __restrict__ b1, const ushort* __restrict__ W2g,
    const float* __restrict__ b2, ushort* __restrict__ Y) {
  __shared__ char lds[3 * BMLP_SLOT + 64 * 260 * 2 + 65536];   // 156.5 KB
  char* C1 = lds + 3 * BMLP_SLOT;
  char* W2s = C1 + 64 * 260 * 2;
  const int tid = threadIdx.x;
  const int lane = tid & 63, wave = tid >> 6;
  const int m0 = blockIdx.x * 64;

  const int srow = lane >> 2;
  const int scolb = ((lane & 3) << 4) ^ ((srow & 3) << 4);   // pre-swizzled src offset

  // stage W2 first (16 loads/thread, 64 KB, content pre-swizzled in global)
#pragma unroll
  for (int i = 0; i < 16; i++)
    gload_lds16(W2g + i * 2048 + wave * 512 + lane * 8, W2s + i * 4096 + wave * 1024);

  // prologue: stage layer-1 K-steps 0,1
#pragma unroll
  for (int kt = 0; kt < 2; kt++) {
    char* As = lds + kt * BMLP_SLOT;
    char* W1s = As + 4096;
    const int k0 = kt * 32;
    gload_lds16(A + (size_t)(m0 + wave * 16 + srow) * 512 + k0 + (scolb >> 1),
                As + wave * 1024);
#pragma unroll
    for (int i = 0; i < 4; i++)
      gload_lds16(W1 + (size_t)(wave * 64 + i * 16 + srow) * 512 + k0 + (scolb >> 1),
                  W1s + wave * 4096 + i * 1024);
  }

  f32x4 acc1[4][4] = {};
  const int fr = lane & 15;
  const int fkb = (lane >> 4) * 16;
  const int fswz = (fr & 3) << 4;

  for (int kt = 0; kt < 16; kt++) {
    if (kt < 15) { asm volatile("s_waitcnt vmcnt(5)" ::: "memory"); }
    else         { asm volatile("s_waitcnt vmcnt(0)" ::: "memory"); }
    __builtin_amdgcn_sched_barrier(0);
    __builtin_amdgcn_s_barrier();
    __builtin_amdgcn_sched_barrier(0);

    const char* As = lds + (kt % 3) * BMLP_SLOT;
    const char* W1s = As + 4096;
    bf16x8 a[4], w[4];
#pragma unroll
    for (int i = 0; i < 4; i++)
      a[i] = *(const bf16x8*)(As + (i * 16 + fr) * 64 + (fkb ^ fswz));
#pragma unroll
    for (int j = 0; j < 4; j++)
      w[j] = *(const bf16x8*)(W1s + (wave * 64 + j * 16 + fr) * 64 + (fkb ^ fswz));

    if (kt + 2 < 16) {
      char* Ad = lds + ((kt + 2) % 3) * BMLP_SLOT;
      char* W1d = Ad + 4096;
      const int k2 = (kt + 2) * 32;
      gload_lds16(A + (size_t)(m0 + wave * 16 + srow) * 512 + k2 + (scolb >> 1),
                  Ad + wave * 1024);
#pragma unroll
      for (int i = 0; i < 4; i++)
        gload_lds16(W1 + (size_t)(wave * 64 + i * 16 + srow) * 512 + k2 + (scolb >> 1),
                    W1d + wave * 4096 + i * 1024);
    }

    asm volatile("s_waitcnt lgkmcnt(0)" ::: "memory");
    __builtin_amdgcn_sched_barrier(0);
    __builtin_amdgcn_s_setprio(1);
#pragma unroll
    for (int i = 0; i < 4; i++)
#pragma unroll
      for (int j = 0; j < 4; j++)
        acc1[i][j] = __builtin_amdgcn_mfma_f32_16x16x32_bf16(a[i], w[j], acc1[i][j], 0, 0, 0);
    __builtin_amdgcn_s_setprio(0);
  }

  // acc1 -> C1 (bias+relu, bf16). C/D: col=lane&15, row=(lane>>4)*4+r.
  const int col_l = lane & 15, row_h = (lane >> 4) * 4;
#pragma unroll
  for (int j = 0; j < 4; j++) {
    int n = wave * 64 + j * 16 + col_l;
    float bs = b1[n];
#pragma unroll
    for (int i = 0; i < 4; i++) {
      int rw = i * 16 + row_h;
#pragma unroll
      for (int r = 0; r < 4; r++)
        *(ushort*)(C1 + (size_t)(rw + r) * 520 + n * 2) = f2b(fmaxf(acc1[i][j][r] + bs, 0.f));
    }
  }
  __syncthreads();

  // layer 2: K=256, all LDS-resident. Wave-tile 64x32, acc2 4x2.
  f32x4 acc2[4][2] = {};
#pragma unroll
  for (int ks = 0; ks < 8; ks++) {
    const int kb = ks * 64 + fkb;
    bf16x8 a2[4], w2[2];
#pragma unroll
    for (int i = 0; i < 4; i++)
      a2[i] = *(const bf16x8*)(C1 + (i * 16 + fr) * 520 + kb);
#pragma unroll
    for (int j = 0; j < 2; j++)
      w2[j] = *(const bf16x8*)(W2s + (wave * 32 + j * 16 + fr) * 512 + (kb ^ ((fr & 7) << 4)));
#pragma unroll
    for (int i = 0; i < 4; i++)
#pragma unroll
      for (int j = 0; j < 2; j++)
        acc2[i][j] = __builtin_amdgcn_mfma_f32_16x16x32_bf16(a2[i], w2[j], acc2[i][j], 0, 0, 0);
  }

#pragma unroll
  for (int j = 0; j < 2; j++) {
    int n = wave * 32 + j * 16 + col_l;
    float bs = b2[n];
#pragma unroll
    for (int i = 0; i < 4; i++) {
      int mb = m0 + i * 16 + row_h;
#pragma unroll
      for (int r = 0; r < 4; r++)
        Y[(size_t)(mb + r) * 128 + n] = f2b(fmaxf(acc2[i][j][r] + bs, 0.f));
    }
  }
}

// ---------------- deep-pipelined bf16 GEMM: BM=256 BN=128 BK=64, 3-slot ring ----------------
#define SLOT_BYTES 49152   // A: 256x64 bf16 = 32KB, B: 128x64 bf16 = 16KB
template <int ACT>
__global__ __launch_bounds__(512, 2) void gemm256_kernel(
    const ushort* __restrict__ A, const ushort* __restrict__ W,
    const float* __restrict__ bias, ushort* __restrict__ C, int K, int ldc) {
  __shared__ char lds[3 * SLOT_BYTES];
  const int tid = threadIdx.x;
  const int lane = tid & 63, wid = tid >> 6;
  const int wm = wid >> 2, wn = wid & 3;

  // bijective XCD-chunked swizzle (m204)
  const int nwg = gridDim.x * gridDim.y;
  const int orig = blockIdx.y * gridDim.x + blockIdx.x;
  const int q = nwg >> 3, r8 = nwg & 7;
  const int xcd = orig & 7, pos = orig >> 3;
  const int swzid = (xcd < r8 ? xcd * (q + 1) : r8 * (q + 1) + (xcd - r8) * q) + pos;
  const int m0 = (swzid / gridDim.x) * 256, n0 = (swzid % gridDim.x) * 128;
  const int NK = K >> 6;

  const int srow = tid >> 3;           // staging row within 64-row group
  const int scolb = (tid & 7) << 4;    // staging col byte 0..112

  // prologue: stage K-steps 0 and 1
#pragma unroll
  for (int kt = 0; kt < 2; kt++) {
    char* As = lds + kt * SLOT_BYTES;
    char* Bs = As + 32768;
    const int k0 = kt * 64;
#pragma unroll
    for (int i = 0; i < 4; i++) {
      int row = i * 64 + srow;
      int colb = scolb ^ ((row & 7) << 4);
      gload_lds16(A + (size_t)(m0 + row) * K + k0 + (colb >> 1), As + i * 8192 + wid * 1024);
    }
#pragma unroll
    for (int i = 0; i < 2; i++) {
      int row = i * 64 + srow;
      int colb = scolb ^ ((row & 7) << 4);
      gload_lds16(W + (size_t)(n0 + row) * K + k0 + (colb >> 1), Bs + i * 8192 + wid * 1024);
    }
  }

  f32x4 acc[8][2] = {};
  const int fr = lane & 15;
  const int fkb = (lane >> 4) * 16;

  for (int kt = 0; kt < NK; kt++) {
    if (kt + 1 < NK) { asm volatile("s_waitcnt vmcnt(6)" ::: "memory"); }
    else             { asm volatile("s_waitcnt vmcnt(0)" ::: "memory"); }
    __builtin_amdgcn_sched_barrier(0);
    __builtin_amdgcn_s_barrier();
    __builtin_amdgcn_sched_barrier(0);

    const char* As = lds + (kt % 3) * SLOT_BYTES;
    const char* Bs = As + 32768;
    char* Ad = lds + ((kt + 2) % 3) * SLOT_BYTES;
    char* Bd = Ad + 32768;
    const int k2 = (kt + 2) * 64;
    const bool do_stage = (kt + 2 < NK);

#pragma unroll
    for (int kh = 0; kh < 2; kh++) {
      bf16x8 a[8], b[2];
#pragma unroll
      for (int mf = 0; mf < 8; mf++) {
        int row = wm * 128 + mf * 16 + fr;
        int colb = (kh * 64 + fkb) ^ ((row & 7) << 4);
        a[mf] = *(const bf16x8*)(As + row * 128 + colb);
      }
#pragma unroll
      for (int nf = 0; nf < 2; nf++) {
        int row = wn * 32 + nf * 16 + fr;
        int colb = (kh * 64 + fkb) ^ ((row & 7) << 4);
        b[nf] = *(const bf16x8*)(Bs + row * 128 + colb);
      }
      if (do_stage) {
#pragma unroll
        for (int i = kh * 2; i < kh * 2 + 2; i++) {
          int row = i * 64 + srow;
          int colb = scolb ^ ((row & 7) << 4);
          gload_lds16(A + (size_t)(m0 + row) * K + k2 + (colb >> 1), Ad + i * 8192 + wid * 1024);
        }
        {
          int row = kh * 64 + srow;
          int colb = scolb ^ ((row & 7) << 4);
          gload_lds16(W + (size_t)(n0 + row) * K + k2 + (colb >> 1), Bd + kh * 8192 + wid * 1024);
        }
      }
      __builtin_amdgcn_sched_barrier(0);
      __builtin_amdgcn_s_barrier();
      asm volatile("s_waitcnt lgkmcnt(0)" ::: "memory");
      __builtin_amdgcn_sched_barrier(0);
      __builtin_amdgcn_s_setprio(1);
#pragma unroll
      for (int mf = 0; mf < 8; mf++)
#pragma unroll
        for (int nf = 0; nf < 2; nf++)
          acc[mf][nf] = __builtin_amdgcn_mfma_f32_16x16x32_bf16(a[mf], b[nf], acc[mf][nf], 0, 0, 0);
      __builtin_amdgcn_s_setprio(0);
      if (kh == 0) {
        __builtin_amdgcn_sched_barrier(0);
        __builtin_amdgcn_s_barrier();
        __builtin_amdgcn_sched_barrier(0);
      }
    }
  }

  const int cr = lane & 15, rh = (lane >> 4) * 4;
#pragma unroll
  for (int nf = 0; nf < 2; nf++) {
    int n = n0 + wn * 32 + nf * 16 + cr;
    float bs = bias[n];
#pragma unroll
    for (int mf = 0; mf < 8; mf++) {
      int mb = m0 + wm * 128 + mf * 16 + rh;
#pragma unroll
      for (int r = 0; r < 4; r++) {
        float v = acc[mf][nf][r] + bs;
        if (ACT) v = fmaxf(v, 0.f);
        C[(size_t)(mb + r) * ldc + n] = f2b(v);
      }
    }
  }
}

// ---------------- fused t2 (512->256 relu) + final (256->1 sigmoid) ----------------
__global__ __launch_bounds__(256) void t2final_kernel(
    const ushort* __restrict__ A, const ushort* __restrict__ W,
    const float* __restrict__ bias, const float* __restrict__ w3,
    const float* __restrict__ b3, float* __restrict__ out) {
  __shared__ char smem[64 * 264 * 2];        // 33.8 KB; As/Bs overlay in front
  ushort* As = (ushort*)smem;                // 64 x 32 (4 KB)
  ushort* Bs = (ushort*)(smem + 4096);       // 256 x 32 (16 KB)
  ushort* Ct = (ushort*)smem;                // 64 x 264 after compute
  const int tid = threadIdx.x;
  const int lane = tid & 63, wave = tid >> 6;
  const int m0 = blockIdx.x * 64;

  const int srow = lane >> 2;
  const int scolb = ((lane & 3) << 4) ^ ((srow & 3) << 4);
  const ushort* Ag = A + (size_t)(m0 + wave * 16 + srow) * 512 + (scolb >> 1);
  const ushort* Wg = W + (size_t)(wave * 16 + srow) * 512 + (scolb >> 1);

  f32x4 acc[4][4] = {};
  const int fr = lane & 15;
  const int fkb = (lane >> 4) * 16;
  const int fswz = (fr & 3) << 4;

  for (int k0 = 0; k0 < 512; k0 += 32) {
    gload_lds16(Ag + k0, (char*)As + wave * 1024);
#pragma unroll
    for (int i = 0; i < 4; i++)
      gload_lds16(Wg + (size_t)(i * 64) * 512 + k0, (char*)Bs + i * 4096 + wave * 1024);
    __syncthreads();
    bf16x8 a[4], b[4];
#pragma unroll
    for (int i = 0; i < 4; i++) {
      a[i] = *(const bf16x8*)((const char*)As + (i * 16 + fr) * 64 + (fkb ^ fswz));
      b[i] = *(const bf16x8*)((const char*)Bs + (wave * 64 + i * 16 + fr) * 64 + (fkb ^ fswz));
    }
#pragma unroll
    for (int i = 0; i < 4; i++)
#pragma unroll
      for (int j = 0; j < 4; j++)
        acc[i][j] = __builtin_amdgcn_mfma_f32_16x16x32_bf16(a[i], b[j], acc[i][j], 0, 0, 0);
    __syncthreads();
  }

  const int col_l = lane & 15, row_h = (lane >> 4) * 4;
#pragma unroll
  for (int j = 0; j < 4; j++) {
    int n = wave * 64 + j * 16 + col_l;
    float bs = bias[n];
#pragma unroll
    for (int i = 0; i < 4; i++) {
      int mb = i * 16 + row_h;
#pragma unroll
      for (int r = 0; r < 4; r++)
        Ct[(size_t)(mb + r) * 264 + n] = f2b(fmaxf(acc[i][j][r] + bs, 0.f));
    }
  }
  __syncthreads();

  const float4 wv = ((const float4*)w3)[lane];
  const float bf = b3[0];
  for (int rr = 0; rr < 16; rr++) {
    int row = wave * 16 + rr;
    ushort4 a4 = *(const ushort4*)&Ct[(size_t)row * 264 + lane * 4];
    float s = b2f(a4.x) * wv.x + b2f(a4.y) * wv.y + b2f(a4.z) * wv.z + b2f(a4.w) * wv.w;
#pragma unroll
    for (int off = 32; off >= 1; off >>= 1) s += __shfl_xor(s, off);
    if (lane == 0) out[m0 + row] = 1.f / (1.f + expf(-(s + bf)));
  }
}

extern "C" void kernel_launch(void* const* d_in, const int* in_sizes, int n_in,
                              void* d_out, int out_size, void* d_ws, size_t ws_size,
                              hipStream_t stream) {
  const float* dense_x = (const float*)d_in[0];
  const int* lS_i = (const int*)d_in[2];
  const float* emb = (const float*)d_in[3];
  const float* bw0 = (const float*)d_in[4];
  const float* bb0 = (const float*)d_in[5];
  const float* bw1 = (const float*)d_in[6];
  const float* bb1 = (const float*)d_in[7];
  const float* bw2 = (const float*)d_in[8];
  const float* bb2 = (const float*)d_in[9];
  const float* tw0 = (const float*)d_in[10];
  const float* tb0 = (const float*)d_in[11];
  const float* tw1 = (const float*)d_in[12];
  const float* tb1 = (const float*)d_in[13];
  const float* tw2 = (const float*)d_in[14];
  const float* tb2 = (const float*)d_in[15];
  const float* tw3 = (const float*)d_in[16];
  const float* tb3 = (const float*)d_in[17];
  float* out = (float*)d_out;

  // workspace layout (bf16)
  char* w = (char*)d_ws;
  ushort* xb  = (ushort*)w; w += (size_t)BATCH * 128 * 2;
  ushort* x1  = (ushort*)w; w += (size_t)BATCH * 512 * 2;
  ushort* x2  = (ushort*)w; w += (size_t)BATCH * 256 * 2;
  ushort* R   = (ushort*)w; w += (size_t)BATCH * 512 * 2;
  ushort* t1  = (ushort*)w; w += (size_t)BATCH * 1024 * 2;
  ushort* wb1 = (ushort*)w; w += 256 * 512 * 2;
  ushort* wb2 = (ushort*)w; w += 128 * 256 * 2;
  ushort* wt0 = (ushort*)w; w += 1024 * 512 * 2;
  ushort* wt1 = (ushort*)w; w += 512 * 1024 * 2;
  ushort* wt2 = (ushort*)w; w += 256 * 512 * 2;
  ushort* t2 = x1;   // reuse (B x 512)
  (void)x2;

  // prep: bot0 + all weight conversions (one launch)
  prep_kernel<<<2 * BATCH + 5 * 2048, 256, 0, stream>>>(
      dense_x, bw0, bb0, x1, bw1, bw2, tw0, tw1, tw2, wb1, wb2, wt0, wt1, wt2);

  // fused bottom MLP 512->256->128 -> xb (packed B x 128)
  bmlp_kernel<<<BATCH / 64, 256, 0, stream>>>(x1, wb1, bb1, wb2, bb2, xb);

  // fused embeddings + interaction -> R = [x | tril(Z) | 0pad]
  embint_kernel<<<BATCH / 4, 256, 0, stream>>>(emb, lS_i, xb, R);

  // top MLP
  gemm256_kernel<1><<<dim3(1024 / 128, BATCH / 256), 512, 0, stream>>>(R,  wt0, tb0, t1, 512, 1024);
  gemm256_kernel<1><<<dim3(512 / 128,  BATCH / 256), 512, 0, stream>>>(t1, wt1, tb1, t2, 1024, 512);
  t2final_kernel<<<BATCH / 64, 256, 0, stream>>>(t2, wt2, tb2, tw3, tb3, out);
}

// Round 11
// 186.621 us; speedup vs baseline: 1.4748x; 1.0972x over previous
//
#include <hip/hip_runtime.h>
#include <hip/hip_bf16.h>
#include <math.h>

#define BATCH 16384
#define NTAB 26
#define DIM 128
#define NROWS 100000

typedef short bf16x8 __attribute__((ext_vector_type(8)));
typedef float f32x4 __attribute__((ext_vector_type(4)));
typedef float f32x16 __attribute__((ext_vector_type(16)));

__device__ __forceinline__ ushort f2b(float f) {   // fp32 -> bf16 RNE
  union { float f; unsigned u; } c; c.f = f;
  unsigned r = (c.u + 0x7fffu + ((c.u >> 16) & 1u)) >> 16;
  return (ushort)r;
}
__device__ __forceinline__ float b2f(ushort u) {
  union { unsigned u; float f; } c; c.u = (unsigned)u << 16;
  return c.f;
}

__device__ __forceinline__ void gload_lds16(const void* g, void* l) {
  __builtin_amdgcn_global_load_lds(
      (const __attribute__((address_space(1))) void*)g,
      (__attribute__((address_space(3))) void*)l, 16, 0, 0);
}

// ---------------- prep: all weight cvt + dense_x pad, one launch, 2D grid ----------------
// o2 (wb2) pre-swizzled: byte ^= ((row&7)<<4) within 512B rows (rule 21 pair with bmlp L2 read).
// dxp/wb0: K 13 -> 32 zero-pad, bf16 (layer-0 via MFMA in bmlp).
__global__ __launch_bounds__(256) void prep_kernel(
    const float* __restrict__ dense_x, const float* __restrict__ bw0,
    const float* __restrict__ bw1, const float* __restrict__ bw2,
    const float* __restrict__ tw0, const float* __restrict__ tw1,
    const float* __restrict__ tw2,
    ushort* __restrict__ dxp, ushort* __restrict__ wb0,
    ushort* __restrict__ o1, ushort* __restrict__ o2, ushort* __restrict__ o3,
    ushort* __restrict__ o4, ushort* __restrict__ o5) {
  int i = blockIdx.x * 256 + threadIdx.x;
  switch (blockIdx.y) {
    case 0: if (i < 256 * 512) o1[i] = f2b(bw1[i]); break;
    case 1: if (i < 128 * 256) {             // pre-swizzled store (W2 for bmlp L2)
      int r = i >> 8, cc = i & 255;
      int db = (((cc << 1) ^ ((r & 7) << 4)) >> 1);
      o2[r * 256 + db] = f2b(bw2[i]);
    } break;
    case 2: if (i < 1024 * 512) {            // pad K 479 -> 512
      int r = i >> 9, cc = i & 511;
      o3[i] = (cc < 479) ? f2b(tw0[(size_t)r * 479 + cc]) : (ushort)0;
    } break;
    case 3: if (i < 512 * 1024) o4[i] = f2b(tw1[i]); break;
    case 4: if (i < 256 * 512) o5[i] = f2b(tw2[i]); break;
    case 5: if (i < BATCH * 32) {            // dense_x [B][13] -> bf16 [B][32] 0-pad
      int r = i >> 5, c = i & 31;
      dxp[i] = (c < 13) ? f2b(dense_x[r * 13 + c]) : (ushort)0;
    } break;
    case 6: if (i < 512 * 32) {              // bw0 [512][13] -> bf16 [512][32] 0-pad
      int r = i >> 5, c = i & 31;
      wb0[i] = (c < 13) ? f2b(bw0[r * 13 + c]) : (ushort)0;
    } break;
  }
}

// ---------------- fused embedding gather+pool+interaction (round-6 form) ----------------
__global__ __launch_bounds__(256) void embint_kernel(
    const float* __restrict__ tables, const int* __restrict__ lS_i,
    const ushort* __restrict__ xb, ushort* __restrict__ R) {
  __shared__ ushort Tls[4][32 * 128];          // 8 KB per wave
  const int wave = threadIdx.x >> 6, lane = threadIdx.x & 63;
  const int b = blockIdx.x * 4 + wave;
  char* tl = (char*)Tls[wave];

  *(uint*)(tl + lane * 4) = *(const uint*)(xb + (size_t)b * 128 + lane * 2);
#pragma unroll
  for (int r = 27; r < 32; r++)
    *(uint*)(tl + r * 256 + ((lane * 4) ^ ((r & 7) << 4))) = 0;
#pragma unroll 8
  for (int t = 0; t < NTAB; t++) {
    const int* idx = lS_i + ((size_t)t << 15) + (b << 1);
    int i0 = idx[0], i1 = idx[1];
    float2 v0 = ((const float2*)(tables + ((size_t)t * NROWS + i0) * DIM))[lane];
    float2 v1 = ((const float2*)(tables + ((size_t)t * NROWS + i1) * DIM))[lane];
    ushort2 s; s.x = f2b(v0.x + v1.x); s.y = f2b(v0.y + v1.y);
    int row = t + 1;
    *(uint*)(tl + row * 256 + ((lane * 4) ^ ((row & 7) << 4))) = *(uint*)&s;
  }
  __syncthreads();

  const int row = lane & 31;
  const int khb = (lane >> 5) * 16;
  const int swz = (row & 7) << 4;
  f32x16 z = {};
#pragma unroll
  for (int ks = 0; ks < 8; ks++) {
    bf16x8 a = *(const bf16x8*)(tl + row * 256 + ((ks * 32 + khb) ^ swz));
    z = __builtin_amdgcn_mfma_f32_32x32x16_bf16(a, a, z, 0, 0, 0);
  }

  ushort* Rb = R + (size_t)b * 512;
  *(uint*)(Rb + lane * 2) = *(const uint*)(tl + lane * 4);
  if (lane < 33) Rb[479 + lane] = 0;
  const int j = lane & 31;
  const int rb4 = (lane >> 5) * 4;
#pragma unroll
  for (int r = 0; r < 16; r++) {
    int i = (r & 3) + 8 * (r >> 2) + rb4;
    if (i <= 26 && j < i) Rb[DIM + (i * (i - 1)) / 2 + j] = f2b(z[r]);
  }
}

// ---------------- fused bottom MLP: 13 -> 512 -> 256 -> 128 (relu each), one kernel ----------------
// 64 batch rows/block, 256 threads = 4 waves.
// Layer 0: K=32 (13 real + 0-pad) single MFMA step from LDS-staged dxp/wb0 tiles;
//          output x1 tile (64x512 bf16) to swizzled x1_lds (R1, 64KB).
// Layer 1: K=512, 16 steps; W1-only 3-slot ring (16KB slots), counted vmcnt(4);
//          A-frags read from x1_lds.  Layer 2: K=256 from C1 (RING overlay) + W2s (R1 overlay).
#define RING_SLOT 16384
__global__ __launch_bounds__(256) void bmlp_kernel(
    const ushort* __restrict__ dxp, const ushort* __restrict__ wb0,
    const float* __restrict__ b0, const ushort* __restrict__ W1,
    const float* __restrict__ b1, const ushort* __restrict__ W2g,
    const float* __restrict__ b2, ushort* __restrict__ Y) {
  __shared__ char lds[65536 + 3 * RING_SLOT + 36864];   // 148 KB
  char* R1 = lds;                               // x1_lds [64][1024B]  -> W2s [128][512B]
  char* RING = lds + 65536;                     // 3 x 16KB W1 slots   -> C1 [64][520B]
  char* wb0s = lds + 65536 + 3 * RING_SLOT;     // [512][64B] 32KB
  char* dxt = wb0s + 32768;                     // [64][64B] 4KB
  const int tid = threadIdx.x;
  const int lane = tid & 63, wave = tid >> 6;
  const int m0 = blockIdx.x * 64;
  const int fr = lane & 15;
  const int kqb = (lane >> 4) * 16;             // k-quarter byte offset
  const int cl = lane & 15, rh = (lane >> 4) * 4;

  // bias pre-loads FIRST (so later counted vmcnt waits never have to keep them)
  float vb0[8], vb1[4], vb2[2];
#pragma unroll
  for (int h = 0; h < 2; h++)
#pragma unroll
    for (int nf = 0; nf < 4; nf++)
      vb0[h * 4 + nf] = b0[wave * 128 + h * 64 + nf * 16 + cl];
#pragma unroll
  for (int j = 0; j < 4; j++) vb1[j] = b1[wave * 64 + j * 16 + cl];
#pragma unroll
  for (int j = 0; j < 2; j++) vb2[j] = b2[wave * 32 + j * 16 + cl];

  // stage wb0s (8 rounds) + dxt (1 round), linear dest
#pragma unroll
  for (int i = 0; i < 8; i++) {
    int flat = i * 4096 + tid * 16;
    int row = flat >> 6, cb = flat & 63;
    gload_lds16(wb0 + row * 32 + (cb >> 1), wb0s + flat);
  }
  {
    int flat = tid * 16;
    int row = flat >> 6, cb = flat & 63;
    gload_lds16(dxp + (size_t)(m0 + row) * 32 + (cb >> 1), dxt + flat);
  }

  // ring prologue: W1 K-steps 0,1 (4 loads each)
  const int srow = lane >> 2;
  const int scolb = ((lane & 3) << 4) ^ ((srow & 3) << 4);
#pragma unroll
  for (int kt = 0; kt < 2; kt++)
#pragma unroll
    for (int i = 0; i < 4; i++)
      gload_lds16(W1 + (size_t)(wave * 64 + i * 16 + srow) * 512 + kt * 32 + (scolb >> 1),
                  RING + kt * RING_SLOT + wave * 4096 + i * 1024);

  // wait dxt/wb0s staged (R3 loads rank <=23 of all outstanding -> always drained), keep ring's 8
  asm volatile("s_waitcnt vmcnt(8)" ::: "memory");
  __builtin_amdgcn_sched_barrier(0);
  __builtin_amdgcn_s_barrier();
  __builtin_amdgcn_sched_barrier(0);

  // ---- layer 0: x1[0:64][wave*128 .. +128] = relu(dxt @ wb0^T + b0), K=32 ----
  {
    bf16x8 a0[4];
#pragma unroll
    for (int mf = 0; mf < 4; mf++)
      a0[mf] = *(const bf16x8*)(dxt + (mf * 16 + fr) * 64 + kqb);
#pragma unroll
    for (int h = 0; h < 2; h++) {
      f32x4 acc0[4][4] = {};
#pragma unroll
      for (int nf = 0; nf < 4; nf++) {
        int wrow = wave * 128 + h * 64 + nf * 16 + fr;
        bf16x8 bb = *(const bf16x8*)(wb0s + wrow * 64 + kqb);
#pragma unroll
        for (int mf = 0; mf < 4; mf++)
          acc0[mf][nf] = __builtin_amdgcn_mfma_f32_16x16x32_bf16(a0[mf], bb, acc0[mf][nf], 0, 0, 0);
      }
#pragma unroll
      for (int nf = 0; nf < 4; nf++) {
        int n = wave * 128 + h * 64 + nf * 16 + cl;
#pragma unroll
        for (int mf = 0; mf < 4; mf++)
#pragma unroll
          for (int r = 0; r < 4; r++) {
            int row = mf * 16 + rh + r;
            float v = fmaxf(acc0[mf][nf][r] + vb0[h * 4 + nf], 0.f);
            *(ushort*)(R1 + row * 1024 + ((2 * n) ^ ((row & 7) << 4))) = f2b(v);
          }
      }
    }
  }
  // publish x1_lds (ring gloads stay in flight: lgkm only)
  asm volatile("s_waitcnt lgkmcnt(0)" ::: "memory");
  __builtin_amdgcn_sched_barrier(0);
  __builtin_amdgcn_s_barrier();
  __builtin_amdgcn_sched_barrier(0);

  // ---- layer 1: K=512, 16 K-steps, ring lookahead 2 ----
  f32x4 acc1[4][4] = {};
  const int fswz = (fr & 3) << 4;
  for (int kt = 0; kt < 16; kt++) {
    if (kt < 15) { asm volatile("s_waitcnt vmcnt(4)" ::: "memory"); }
    else         { asm volatile("s_waitcnt vmcnt(0)" ::: "memory"); }
    __builtin_amdgcn_sched_barrier(0);
    __builtin_amdgcn_s_barrier();
    __builtin_amdgcn_sched_barrier(0);

    const char* W1s = RING + (kt % 3) * RING_SLOT;
    bf16x8 a[4], w[4];
#pragma unroll
    for (int i = 0; i < 4; i++) {
      int row = i * 16 + fr;
      a[i] = *(const bf16x8*)(R1 + row * 1024 + ((kt * 64 + kqb) ^ ((row & 7) << 4)));
    }
#pragma unroll
    for (int j = 0; j < 4; j++)
      w[j] = *(const bf16x8*)(W1s + (wave * 64 + j * 16 + fr) * 64 + (kqb ^ fswz));

    if (kt + 2 < 16) {
#pragma unroll
      for (int i = 0; i < 4; i++)
        gload_lds16(W1 + (size_t)(wave * 64 + i * 16 + srow) * 512 + (kt + 2) * 32 + (scolb >> 1),
                    RING + ((kt + 2) % 3) * RING_SLOT + wave * 4096 + i * 1024);
    }

    asm volatile("s_waitcnt lgkmcnt(0)" ::: "memory");
    __builtin_amdgcn_sched_barrier(0);
    __builtin_amdgcn_s_setprio(1);
#pragma unroll
    for (int i = 0; i < 4; i++)
#pragma unroll
      for (int j = 0; j < 4; j++)
        acc1[i][j] = __builtin_amdgcn_mfma_f32_16x16x32_bf16(a[i], w[j], acc1[i][j], 0, 0, 0);
    __builtin_amdgcn_s_setprio(0);
  }

  // all waves done reading RING/R1 before overlaying them
  __builtin_amdgcn_s_barrier();

  // issue W2 stage into R1 (pre-swizzled content, linear dest)
#pragma unroll
  for (int i = 0; i < 16; i++)
    gload_lds16(W2g + i * 2048 + tid * 8, R1 + i * 4096 + tid * 16);

  // C1 (64 x 520B) overlays RING
  char* C1 = RING;
#pragma unroll
  for (int j = 0; j < 4; j++) {
    int n = wave * 64 + j * 16 + cl;
#pragma unroll
    for (int i = 0; i < 4; i++) {
      int rw = i * 16 + rh;
#pragma unroll
      for (int r = 0; r < 4; r++)
        *(ushort*)(C1 + (size_t)(rw + r) * 520 + n * 2) = f2b(fmaxf(acc1[i][j][r] + vb1[j], 0.f));
    }
  }
  __syncthreads();   // drains W2 vmcnt + C1 lgkm + barrier

  // ---- layer 2: K=256, LDS-resident ----
  f32x4 acc2[4][2] = {};
#pragma unroll
  for (int ks = 0; ks < 8; ks++) {
    const int kb = ks * 64 + kqb;
    bf16x8 a2[4], w2[2];
#pragma unroll
    for (int i = 0; i < 4; i++)
      a2[i] = *(const bf16x8*)(C1 + (i * 16 + fr) * 520 + kb);
#pragma unroll
    for (int j = 0; j < 2; j++)
      w2[j] = *(const bf16x8*)(R1 + (wave * 32 + j * 16 + fr) * 512 + (kb ^ ((fr & 7) << 4)));
#pragma unroll
    for (int i = 0; i < 4; i++)
#pragma unroll
      for (int j = 0; j < 2; j++)
        acc2[i][j] = __builtin_amdgcn_mfma_f32_16x16x32_bf16(a2[i], w2[j], acc2[i][j], 0, 0, 0);
  }
#pragma unroll
  for (int j = 0; j < 2; j++) {
    int n = wave * 32 + j * 16 + cl;
#pragma unroll
    for (int i = 0; i < 4; i++) {
      int mb = m0 + i * 16 + rh;
#pragma unroll
      for (int r = 0; r < 4; r++)
        Y[(size_t)(mb + r) * 128 + n] = f2b(fmaxf(acc2[i][j][r] + vb2[j], 0.f));
    }
  }
}

// ---------------- deep-pipelined bf16 GEMM: BM=256 BN=128 BK=64, 3-slot ring ----------------
#define SLOT_BYTES 49152   // A: 256x64 bf16 = 32KB, B: 128x64 bf16 = 16KB
template <int ACT>
__global__ __launch_bounds__(512, 2) void gemm256_kernel(
    const ushort* __restrict__ A, const ushort* __restrict__ W,
    const float* __restrict__ bias, ushort* __restrict__ C, int K, int ldc) {
  __shared__ char lds[3 * SLOT_BYTES];
  const int tid = threadIdx.x;
  const int lane = tid & 63, wid = tid >> 6;
  const int wm = wid >> 2, wn = wid & 3;

  // bijective XCD-chunked swizzle (m204)
  const int nwg = gridDim.x * gridDim.y;
  const int orig = blockIdx.y * gridDim.x + blockIdx.x;
  const int q = nwg >> 3, r8 = nwg & 7;
  const int xcd = orig & 7, pos = orig >> 3;
  const int swzid = (xcd < r8 ? xcd * (q + 1) : r8 * (q + 1) + (xcd - r8) * q) + pos;
  const int m0 = (swzid / gridDim.x) * 256, n0 = (swzid % gridDim.x) * 128;
  const int NK = K >> 6;

  const int srow = tid >> 3;           // staging row within 64-row group
  const int scolb = (tid & 7) << 4;    // staging col byte 0..112

  // prologue: stage K-steps 0 and 1
#pragma unroll
  for (int kt = 0; kt < 2; kt++) {
    char* As = lds + kt * SLOT_BYTES;
    char* Bs = As + 32768;
    const int k0 = kt * 64;
#pragma unroll
    for (int i = 0; i < 4; i++) {
      int row = i * 64 + srow;
      int colb = scolb ^ ((row & 7) << 4);
      gload_lds16(A + (size_t)(m0 + row) * K + k0 + (colb >> 1), As + i * 8192 + wid * 1024);
    }
#pragma unroll
    for (int i = 0; i < 2; i++) {
      int row = i * 64 + srow;
      int colb = scolb ^ ((row & 7) << 4);
      gload_lds16(W + (size_t)(n0 + row) * K + k0 + (colb >> 1), Bs + i * 8192 + wid * 1024);
    }
  }

  f32x4 acc[8][2] = {};
  const int fr = lane & 15;
  const int fkb = (lane >> 4) * 16;

  for (int kt = 0; kt < NK; kt++) {
    if (kt + 1 < NK) { asm volatile("s_waitcnt vmcnt(6)" ::: "memory"); }
    else             { asm volatile("s_waitcnt vmcnt(0)" ::: "memory"); }
    __builtin_amdgcn_sched_barrier(0);
    __builtin_amdgcn_s_barrier();
    __builtin_amdgcn_sched_barrier(0);

    const char* As = lds + (kt % 3) * SLOT_BYTES;
    const char* Bs = As + 32768;
    char* Ad = lds + ((kt + 2) % 3) * SLOT_BYTES;
    char* Bd = Ad + 32768;
    const int k2 = (kt + 2) * 64;
    const bool do_stage = (kt + 2 < NK);

#pragma unroll
    for (int kh = 0; kh < 2; kh++) {
      bf16x8 a[8], b[2];
#pragma unroll
      for (int mf = 0; mf < 8; mf++) {
        int row = wm * 128 + mf * 16 + fr;
        int colb = (kh * 64 + fkb) ^ ((row & 7) << 4);
        a[mf] = *(const bf16x8*)(As + row * 128 + colb);
      }
#pragma unroll
      for (int nf = 0; nf < 2; nf++) {
        int row = wn * 32 + nf * 16 + fr;
        int colb = (kh * 64 + fkb) ^ ((row & 7) << 4);
        b[nf] = *(const bf16x8*)(Bs + row * 128 + colb);
      }
      if (do_stage) {
#pragma unroll
        for (int i = kh * 2; i < kh * 2 + 2; i++) {
          int row = i * 64 + srow;
          int colb = scolb ^ ((row & 7) << 4);
          gload_lds16(A + (size_t)(m0 + row) * K + k2 + (colb >> 1), Ad + i * 8192 + wid * 1024);
        }
        {
          int row = kh * 64 + srow;
          int colb = scolb ^ ((row & 7) << 4);
          gload_lds16(W + (size_t)(n0 + row) * K + k2 + (colb >> 1), Bd + kh * 8192 + wid * 1024);
        }
      }
      __builtin_amdgcn_sched_barrier(0);
      __builtin_amdgcn_s_barrier();
      asm volatile("s_waitcnt lgkmcnt(0)" ::: "memory");
      __builtin_amdgcn_sched_barrier(0);
      __builtin_amdgcn_s_setprio(1);
#pragma unroll
      for (int mf = 0; mf < 8; mf++)
#pragma unroll
        for (int nf = 0; nf < 2; nf++)
          acc[mf][nf] = __builtin_amdgcn_mfma_f32_16x16x32_bf16(a[mf], b[nf], acc[mf][nf], 0, 0, 0);
      __builtin_amdgcn_s_setprio(0);
      if (kh == 0) {
        __builtin_amdgcn_sched_barrier(0);
        __builtin_amdgcn_s_barrier();
        __builtin_amdgcn_sched_barrier(0);
      }
    }
  }

  const int cr = lane & 15, rh = (lane >> 4) * 4;
#pragma unroll
  for (int nf = 0; nf < 2; nf++) {
    int n = n0 + wn * 32 + nf * 16 + cr;
    float bs = bias[n];
#pragma unroll
    for (int mf = 0; mf < 8; mf++) {
      int mb = m0 + wm * 128 + mf * 16 + rh;
#pragma unroll
      for (int r = 0; r < 4; r++) {
        float v = acc[mf][nf][r] + bs;
        if (ACT) v = fmaxf(v, 0.f);
        C[(size_t)(mb + r) * ldc + n] = f2b(v);
      }
    }
  }
}

// ---------------- fused t2 (512->256 relu) + final (256->1 sigmoid) ----------------
__global__ __launch_bounds__(256) void t2final_kernel(
    const ushort* __restrict__ A, const ushort* __restrict__ W,
    const float* __restrict__ bias, const float* __restrict__ w3,
    const float* __restrict__ b3, float* __restrict__ out) {
  __shared__ char smem[64 * 264 * 2];        // 33.8 KB; As/Bs overlay in front
  ushort* As = (ushort*)smem;                // 64 x 32 (4 KB)
  ushort* Bs = (ushort*)(smem + 4096);       // 256 x 32 (16 KB)
  ushort* Ct = (ushort*)smem;                // 64 x 264 after compute
  const int tid = threadIdx.x;
  const int lane = tid & 63, wave = tid >> 6;
  const int m0 = blockIdx.x * 64;

  const int srow = lane >> 2;
  const int scolb = ((lane & 3) << 4) ^ ((srow & 3) << 4);
  const ushort* Ag = A + (size_t)(m0 + wave * 16 + srow) * 512 + (scolb >> 1);
  const ushort* Wg = W + (size_t)(wave * 16 + srow) * 512 + (scolb >> 1);

  f32x4 acc[4][4] = {};
  const int fr = lane & 15;
  const int fkb = (lane >> 4) * 16;
  const int fswz = (fr & 3) << 4;

  for (int k0 = 0; k0 < 512; k0 += 32) {
    gload_lds16(Ag + k0, (char*)As + wave * 1024);
#pragma unroll
    for (int i = 0; i < 4; i++)
      gload_lds16(Wg + (size_t)(i * 64) * 512 + k0, (char*)Bs + i * 4096 + wave * 1024);
    __syncthreads();
    bf16x8 a[4], b[4];
#pragma unroll
    for (int i = 0; i < 4; i++) {
      a[i] = *(const bf16x8*)((const char*)As + (i * 16 + fr) * 64 + (fkb ^ fswz));
      b[i] = *(const bf16x8*)((const char*)Bs + (wave * 64 + i * 16 + fr) * 64 + (fkb ^ fswz));
    }
#pragma unroll
    for (int i = 0; i < 4; i++)
#pragma unroll
      for (int j = 0; j < 4; j++)
        acc[i][j] = __builtin_amdgcn_mfma_f32_16x16x32_bf16(a[i], b[j], acc[i][j], 0, 0, 0);
    __syncthreads();
  }

  const int col_l = lane & 15, row_h = (lane >> 4) * 4;
#pragma unroll
  for (int j = 0; j < 4; j++) {
    int n = wave * 64 + j * 16 + col_l;
    float bs = bias[n];
#pragma unroll
    for (int i = 0; i < 4; i++) {
      int mb = i * 16 + row_h;
#pragma unroll
      for (int r = 0; r < 4; r++)
        Ct[(size_t)(mb + r) * 264 + n] = f2b(fmaxf(acc[i][j][r] + bs, 0.f));
    }
  }
  __syncthreads();

  const float4 wv = ((const float4*)w3)[lane];
  const float bf = b3[0];
  for (int rr = 0; rr < 16; rr++) {
    int row = wave * 16 + rr;
    ushort4 a4 = *(const ushort4*)&Ct[(size_t)row * 264 + lane * 4];
    float s = b2f(a4.x) * wv.x + b2f(a4.y) * wv.y + b2f(a4.z) * wv.z + b2f(a4.w) * wv.w;
#pragma unroll
    for (int off = 32; off >= 1; off >>= 1) s += __shfl_xor(s, off);
    if (lane == 0) out[m0 + row] = 1.f / (1.f + expf(-(s + bf)));
  }
}

extern "C" void kernel_launch(void* const* d_in, const int* in_sizes, int n_in,
                              void* d_out, int out_size, void* d_ws, size_t ws_size,
                              hipStream_t stream) {
  const float* dense_x = (const float*)d_in[0];
  const int* lS_i = (const int*)d_in[2];
  const float* emb = (const float*)d_in[3];
  const float* bw0 = (const float*)d_in[4];
  const float* bb0 = (const float*)d_in[5];
  const float* bw1 = (const float*)d_in[6];
  const float* bb1 = (const float*)d_in[7];
  const float* bw2 = (const float*)d_in[8];
  const float* bb2 = (const float*)d_in[9];
  const float* tw0 = (const float*)d_in[10];
  const float* tb0 = (const float*)d_in[11];
  const float* tw1 = (const float*)d_in[12];
  const float* tb1 = (const float*)d_in[13];
  const float* tw2 = (const float*)d_in[14];
  const float* tb2 = (const float*)d_in[15];
  const float* tw3 = (const float*)d_in[16];
  const float* tb3 = (const float*)d_in[17];
  float* out = (float*)d_out;

  // workspace layout (bf16)
  char* w = (char*)d_ws;
  ushort* xb  = (ushort*)w; w += (size_t)BATCH * 128 * 2;
  ushort* x1  = (ushort*)w; w += (size_t)BATCH * 512 * 2;   // reused as t2
  ushort* x2  = (ushort*)w; w += (size_t)BATCH * 256 * 2;   // unused
  ushort* R   = (ushort*)w; w += (size_t)BATCH * 512 * 2;
  ushort* t1  = (ushort*)w; w += (size_t)BATCH * 1024 * 2;
  ushort* wb1 = (ushort*)w; w += 256 * 512 * 2;
  ushort* wb2 = (ushort*)w; w += 128 * 256 * 2;
  ushort* wt0 = (ushort*)w; w += 1024 * 512 * 2;
  ushort* wt1 = (ushort*)w; w += 512 * 1024 * 2;
  ushort* wt2 = (ushort*)w; w += 256 * 512 * 2;
  ushort* dxp = (ushort*)w; w += (size_t)BATCH * 32 * 2;
  ushort* wb0 = (ushort*)w; w += 512 * 32 * 2;
  ushort* t2 = x1;
  (void)x2;

  // prep: all conversions + dense_x pad (one launch)
  prep_kernel<<<dim3(2048, 7), 256, 0, stream>>>(
      dense_x, bw0, bw1, bw2, tw0, tw1, tw2, dxp, wb0,
      wb1, wb2, wt0, wt1, wt2);

  // fused bottom MLP 13->512->256->128 -> xb (packed B x 128)
  bmlp_kernel<<<BATCH / 64, 256, 0, stream>>>(dxp, wb0, bb0, wb1, bb1, wb2, bb2, xb);

  // fused embeddings + interaction -> R = [x | tril(Z) | 0pad]
  embint_kernel<<<BATCH / 4, 256, 0, stream>>>(emb, lS_i, xb, R);

  // top MLP
  gemm256_kernel<1><<<dim3(1024 / 128, BATCH / 256), 512, 0, stream>>>(R,  wt0, tb0, t1, 512, 1024);
  gemm256_kernel<1><<<dim3(512 / 128,  BATCH / 256), 512, 0, stream>>>(t1, wt1, tb1, t2, 1024, 512);
  t2final_kernel<<<BATCH / 64, 256, 0, stream>>>(t2, wt2, tb2, tw3, tb3, out);
}

// Round 12
// 186.105 us; speedup vs baseline: 1.4789x; 1.0028x over previous
//
#include <hip/hip_runtime.h>
#include <hip/hip_bf16.h>
#include <math.h>

#define BATCH 16384
#define NTAB 26
#define DIM 128
#define NROWS 100000

typedef short bf16x8 __attribute__((ext_vector_type(8)));
typedef float f32x4 __attribute__((ext_vector_type(4)));
typedef float f32x16 __attribute__((ext_vector_type(16)));

__device__ __forceinline__ ushort f2b(float f) {   // fp32 -> bf16 RNE
  union { float f; unsigned u; } c; c.f = f;
  unsigned r = (c.u + 0x7fffu + ((c.u >> 16) & 1u)) >> 16;
  return (ushort)r;
}
__device__ __forceinline__ float b2f(ushort u) {
  union { unsigned u; float f; } c; c.u = (unsigned)u << 16;
  return c.f;
}

__device__ __forceinline__ void gload_lds16(const void* g, void* l) {
  __builtin_amdgcn_global_load_lds(
      (const __attribute__((address_space(1))) void*)g,
      (__attribute__((address_space(3))) void*)l, 16, 0, 0);
}

// ---------------- prep: all weight cvt + dense_x pad, one launch, 2D grid ----------------
// o2 (wb2) pre-swizzled: byte ^= ((row&7)<<4) within 512B rows (rule 21 pair with bmlp L2 read).
// dxp/wb0: K 13 -> 32 zero-pad, bf16 (layer-0 via MFMA in bmlp).
__global__ __launch_bounds__(256) void prep_kernel(
    const float* __restrict__ dense_x, const float* __restrict__ bw0,
    const float* __restrict__ bw1, const float* __restrict__ bw2,
    const float* __restrict__ tw0, const float* __restrict__ tw1,
    const float* __restrict__ tw2,
    ushort* __restrict__ dxp, ushort* __restrict__ wb0,
    ushort* __restrict__ o1, ushort* __restrict__ o2, ushort* __restrict__ o3,
    ushort* __restrict__ o4, ushort* __restrict__ o5) {
  int i = blockIdx.x * 256 + threadIdx.x;
  switch (blockIdx.y) {
    case 0: if (i < 256 * 512) o1[i] = f2b(bw1[i]); break;
    case 1: if (i < 128 * 256) {             // pre-swizzled store (W2 for bmlp L2)
      int r = i >> 8, cc = i & 255;
      int db = (((cc << 1) ^ ((r & 7) << 4)) >> 1);
      o2[r * 256 + db] = f2b(bw2[i]);
    } break;
    case 2: if (i < 1024 * 512) {            // pad K 479 -> 512
      int r = i >> 9, cc = i & 511;
      o3[i] = (cc < 479) ? f2b(tw0[(size_t)r * 479 + cc]) : (ushort)0;
    } break;
    case 3: if (i < 512 * 1024) o4[i] = f2b(tw1[i]); break;
    case 4: if (i < 256 * 512) o5[i] = f2b(tw2[i]); break;
    case 5: if (i < BATCH * 32) {            // dense_x [B][13] -> bf16 [B][32] 0-pad
      int r = i >> 5, c = i & 31;
      dxp[i] = (c < 13) ? f2b(dense_x[r * 13 + c]) : (ushort)0;
    } break;
    case 6: if (i < 512 * 32) {              // bw0 [512][13] -> bf16 [512][32] 0-pad
      int r = i >> 5, c = i & 31;
      wb0[i] = (c < 13) ? f2b(bw0[r * 13 + c]) : (ushort)0;
    } break;
  }
}

// ---------------- fused embedding gather+pool+interaction (round-6 form) ----------------
__global__ __launch_bounds__(256) void embint_kernel(
    const float* __restrict__ tables, const int* __restrict__ lS_i,
    const ushort* __restrict__ xb, ushort* __restrict__ R) {
  __shared__ ushort Tls[4][32 * 128];          // 8 KB per wave
  const int wave = threadIdx.x >> 6, lane = threadIdx.x & 63;
  const int b = blockIdx.x * 4 + wave;
  char* tl = (char*)Tls[wave];

  *(uint*)(tl + lane * 4) = *(const uint*)(xb + (size_t)b * 128 + lane * 2);
#pragma unroll
  for (int r = 27; r < 32; r++)
    *(uint*)(tl + r * 256 + ((lane * 4) ^ ((r & 7) << 4))) = 0;
#pragma unroll 8
  for (int t = 0; t < NTAB; t++) {
    const int* idx = lS_i + ((size_t)t << 15) + (b << 1);
    int i0 = idx[0], i1 = idx[1];
    float2 v0 = ((const float2*)(tables + ((size_t)t * NROWS + i0) * DIM))[lane];
    float2 v1 = ((const float2*)(tables + ((size_t)t * NROWS + i1) * DIM))[lane];
    ushort2 s; s.x = f2b(v0.x + v1.x); s.y = f2b(v0.y + v1.y);
    int row = t + 1;
    *(uint*)(tl + row * 256 + ((lane * 4) ^ ((row & 7) << 4))) = *(uint*)&s;
  }
  __syncthreads();

  const int row = lane & 31;
  const int khb = (lane >> 5) * 16;
  const int swz = (row & 7) << 4;
  f32x16 z = {};
#pragma unroll
  for (int ks = 0; ks < 8; ks++) {
    bf16x8 a = *(const bf16x8*)(tl + row * 256 + ((ks * 32 + khb) ^ swz));
    z = __builtin_amdgcn_mfma_f32_32x32x16_bf16(a, a, z, 0, 0, 0);
  }

  ushort* Rb = R + (size_t)b * 512;
  *(uint*)(Rb + lane * 2) = *(const uint*)(tl + lane * 4);
  if (lane < 33) Rb[479 + lane] = 0;
  const int j = lane & 31;
  const int rb4 = (lane >> 5) * 4;
#pragma unroll
  for (int r = 0; r < 16; r++) {
    int i = (r & 3) + 8 * (r >> 2) + rb4;
    if (i <= 26 && j < i) Rb[DIM + (i * (i - 1)) / 2 + j] = f2b(z[r]);
  }
}

// ---------------- fused bottom MLP: 13 -> 512 -> 256 -> 128 (relu each), one kernel ----------------
#define RING_SLOT 16384
__global__ __launch_bounds__(256) void bmlp_kernel(
    const ushort* __restrict__ dxp, const ushort* __restrict__ wb0,
    const float* __restrict__ b0, const ushort* __restrict__ W1,
    const float* __restrict__ b1, const ushort* __restrict__ W2g,
    const float* __restrict__ b2, ushort* __restrict__ Y) {
  __shared__ char lds[65536 + 3 * RING_SLOT + 36864];   // 148 KB
  char* R1 = lds;                               // x1_lds [64][1024B]  -> W2s [128][512B]
  char* RING = lds + 65536;                     // 3 x 16KB W1 slots   -> C1 [64][520B]
  char* wb0s = lds + 65536 + 3 * RING_SLOT;     // [512][64B] 32KB
  char* dxt = wb0s + 32768;                     // [64][64B] 4KB
  const int tid = threadIdx.x;
  const int lane = tid & 63, wave = tid >> 6;
  const int m0 = blockIdx.x * 64;
  const int fr = lane & 15;
  const int kqb = (lane >> 4) * 16;             // k-quarter byte offset
  const int cl = lane & 15, rh = (lane >> 4) * 4;

  // bias pre-loads FIRST (so later counted vmcnt waits never have to keep them)
  float vb0[8], vb1[4], vb2[2];
#pragma unroll
  for (int h = 0; h < 2; h++)
#pragma unroll
    for (int nf = 0; nf < 4; nf++)
      vb0[h * 4 + nf] = b0[wave * 128 + h * 64 + nf * 16 + cl];
#pragma unroll
  for (int j = 0; j < 4; j++) vb1[j] = b1[wave * 64 + j * 16 + cl];
#pragma unroll
  for (int j = 0; j < 2; j++) vb2[j] = b2[wave * 32 + j * 16 + cl];

  // stage wb0s (8 rounds) + dxt (1 round), linear dest
#pragma unroll
  for (int i = 0; i < 8; i++) {
    int flat = i * 4096 + tid * 16;
    int row = flat >> 6, cb = flat & 63;
    gload_lds16(wb0 + row * 32 + (cb >> 1), wb0s + flat);
  }
  {
    int flat = tid * 16;
    int row = flat >> 6, cb = flat & 63;
    gload_lds16(dxp + (size_t)(m0 + row) * 32 + (cb >> 1), dxt + flat);
  }

  // ring prologue: W1 K-steps 0,1 (4 loads each)
  const int srow = lane >> 2;
  const int scolb = ((lane & 3) << 4) ^ ((srow & 3) << 4);
#pragma unroll
  for (int kt = 0; kt < 2; kt++)
#pragma unroll
    for (int i = 0; i < 4; i++)
      gload_lds16(W1 + (size_t)(wave * 64 + i * 16 + srow) * 512 + kt * 32 + (scolb >> 1),
                  RING + kt * RING_SLOT + wave * 4096 + i * 1024);

  // wait dxt/wb0s staged, keep ring's 8
  asm volatile("s_waitcnt vmcnt(8)" ::: "memory");
  __builtin_amdgcn_sched_barrier(0);
  __builtin_amdgcn_s_barrier();
  __builtin_amdgcn_sched_barrier(0);

  // ---- layer 0: x1[0:64][wave*128 .. +128] = relu(dxt @ wb0^T + b0), K=32 ----
  {
    bf16x8 a0[4];
#pragma unroll
    for (int mf = 0; mf < 4; mf++)
      a0[mf] = *(const bf16x8*)(dxt + (mf * 16 + fr) * 64 + kqb);
#pragma unroll
    for (int h = 0; h < 2; h++) {
      f32x4 acc0[4][4] = {};
#pragma unroll
      for (int nf = 0; nf < 4; nf++) {
        int wrow = wave * 128 + h * 64 + nf * 16 + fr;
        bf16x8 bb = *(const bf16x8*)(wb0s + wrow * 64 + kqb);
#pragma unroll
        for (int mf = 0; mf < 4; mf++)
          acc0[mf][nf] = __builtin_amdgcn_mfma_f32_16x16x32_bf16(a0[mf], bb, acc0[mf][nf], 0, 0, 0);
      }
#pragma unroll
      for (int nf = 0; nf < 4; nf++) {
        int n = wave * 128 + h * 64 + nf * 16 + cl;
#pragma unroll
        for (int mf = 0; mf < 4; mf++)
#pragma unroll
          for (int r = 0; r < 4; r++) {
            int row = mf * 16 + rh + r;
            float v = fmaxf(acc0[mf][nf][r] + vb0[h * 4 + nf], 0.f);
            *(ushort*)(R1 + row * 1024 + ((2 * n) ^ ((row & 7) << 4))) = f2b(v);
          }
      }
    }
  }
  // publish x1_lds (ring gloads stay in flight: lgkm only)
  asm volatile("s_waitcnt lgkmcnt(0)" ::: "memory");
  __builtin_amdgcn_sched_barrier(0);
  __builtin_amdgcn_s_barrier();
  __builtin_amdgcn_sched_barrier(0);

  // ---- layer 1: K=512, 16 K-steps, ring lookahead 2 ----
  f32x4 acc1[4][4] = {};
  const int fswz = (fr & 3) << 4;
  for (int kt = 0; kt < 16; kt++) {
    if (kt < 15) { asm volatile("s_waitcnt vmcnt(4)" ::: "memory"); }
    else         { asm volatile("s_waitcnt vmcnt(0)" ::: "memory"); }
    __builtin_amdgcn_sched_barrier(0);
    __builtin_amdgcn_s_barrier();
    __builtin_amdgcn_sched_barrier(0);

    const char* W1s = RING + (kt % 3) * RING_SLOT;
    bf16x8 a[4], w[4];
#pragma unroll
    for (int i = 0; i < 4; i++) {
      int row = i * 16 + fr;
      a[i] = *(const bf16x8*)(R1 + row * 1024 + ((kt * 64 + kqb) ^ ((row & 7) << 4)));
    }
#pragma unroll
    for (int j = 0; j < 4; j++)
      w[j] = *(const bf16x8*)(W1s + (wave * 64 + j * 16 + fr) * 64 + (kqb ^ fswz));

    if (kt + 2 < 16) {
#pragma unroll
      for (int i = 0; i < 4; i++)
        gload_lds16(W1 + (size_t)(wave * 64 + i * 16 + srow) * 512 + (kt + 2) * 32 + (scolb >> 1),
                    RING + ((kt + 2) % 3) * RING_SLOT + wave * 4096 + i * 1024);
    }

    asm volatile("s_waitcnt lgkmcnt(0)" ::: "memory");
    __builtin_amdgcn_sched_barrier(0);
    __builtin_amdgcn_s_setprio(1);
#pragma unroll
    for (int i = 0; i < 4; i++)
#pragma unroll
      for (int j = 0; j < 4; j++)
        acc1[i][j] = __builtin_amdgcn_mfma_f32_16x16x32_bf16(a[i], w[j], acc1[i][j], 0, 0, 0);
    __builtin_amdgcn_s_setprio(0);
  }

  // all waves done reading RING/R1 before overlaying them
  __builtin_amdgcn_s_barrier();

  // issue W2 stage into R1 (pre-swizzled content, linear dest)
#pragma unroll
  for (int i = 0; i < 16; i++)
    gload_lds16(W2g + i * 2048 + tid * 8, R1 + i * 4096 + tid * 16);

  // C1 (64 x 520B) overlays RING
  char* C1 = RING;
#pragma unroll
  for (int j = 0; j < 4; j++) {
    int n = wave * 64 + j * 16 + cl;
#pragma unroll
    for (int i = 0; i < 4; i++) {
      int rw = i * 16 + rh;
#pragma unroll
      for (int r = 0; r < 4; r++)
        *(ushort*)(C1 + (size_t)(rw + r) * 520 + n * 2) = f2b(fmaxf(acc1[i][j][r] + vb1[j], 0.f));
    }
  }
  __syncthreads();   // drains W2 vmcnt + C1 lgkm + barrier

  // ---- layer 2: K=256, LDS-resident ----
  f32x4 acc2[4][2] = {};
#pragma unroll
  for (int ks = 0; ks < 8; ks++) {
    const int kb = ks * 64 + kqb;
    bf16x8 a2[4], w2[2];
#pragma unroll
    for (int i = 0; i < 4; i++)
      a2[i] = *(const bf16x8*)(C1 + (i * 16 + fr) * 520 + kb);
#pragma unroll
    for (int j = 0; j < 2; j++)
      w2[j] = *(const bf16x8*)(R1 + (wave * 32 + j * 16 + fr) * 512 + (kb ^ ((fr & 7) << 4)));
#pragma unroll
    for (int i = 0; i < 4; i++)
#pragma unroll
      for (int j = 0; j < 2; j++)
        acc2[i][j] = __builtin_amdgcn_mfma_f32_16x16x32_bf16(a2[i], w2[j], acc2[i][j], 0, 0, 0);
  }
#pragma unroll
  for (int j = 0; j < 2; j++) {
    int n = wave * 32 + j * 16 + cl;
#pragma unroll
    for (int i = 0; i < 4; i++) {
      int mb = m0 + i * 16 + rh;
#pragma unroll
      for (int r = 0; r < 4; r++)
        Y[(size_t)(mb + r) * 128 + n] = f2b(fmaxf(acc2[i][j][r] + vb2[j], 0.f));
    }
  }
}

// ---------------- deep-pipelined bf16 GEMM: BM=256 BN=128 BK=32, 3-slot ring ----------------
// 72 KB LDS -> 2 blocks/CU (16 waves/CU). 3 loads/K-step, counted vmcnt(3) lookahead-2,
// ONE barrier per K-step (bmlp-L1 discipline). Same K=32 accumulation order as BK=64
// (bit-identical output). Swizzle: 64B rows, (row&3)<<4 XOR, pre-swizzled source.
#define SLOT_BYTES 24576   // A: 256x32 bf16 = 16KB, B: 128x32 bf16 = 8KB
template <int ACT>
__global__ __launch_bounds__(512, 4) void gemm256_kernel(
    const ushort* __restrict__ A, const ushort* __restrict__ W,
    const float* __restrict__ bias, ushort* __restrict__ C, int K, int ldc) {
  __shared__ char lds[3 * SLOT_BYTES];
  const int tid = threadIdx.x;
  const int lane = tid & 63, wid = tid >> 6;
  const int wm = wid >> 2, wn = wid & 3;

  // bijective XCD-chunked swizzle (m204)
  const int nwg = gridDim.x * gridDim.y;
  const int orig = blockIdx.y * gridDim.x + blockIdx.x;
  const int q = nwg >> 3, r8 = nwg & 7;
  const int xcd = orig & 7, pos = orig >> 3;
  const int swzid = (xcd < r8 ? xcd * (q + 1) : r8 * (q + 1) + (xcd - r8) * q) + pos;
  const int m0 = (swzid / gridDim.x) * 256, n0 = (swzid % gridDim.x) * 128;
  const int NK = K >> 5;

  // staging geometry (64B rows): A = 2 rounds of 8KB, B = 1 round
  const int arow0 = tid >> 2;            // flat row for round 0 (rows 0..127)
  const int acb = (tid & 3) << 4;        // col byte 0..48

  f32x4 acc[8][2] = {};
  const int fr = lane & 15;
  const int kqb = (lane >> 4) * 16;

  // prologue: stage K-steps 0 and 1
#pragma unroll
  for (int kt = 0; kt < 2; kt++) {
    char* As = lds + kt * SLOT_BYTES;
    char* Bs = As + 16384;
    const int k0 = kt * 32;
#pragma unroll
    for (int i = 0; i < 2; i++) {
      int row = i * 128 + arow0;
      int cb = acb ^ ((row & 3) << 4);
      gload_lds16(A + (size_t)(m0 + row) * K + k0 + (cb >> 1), As + i * 8192 + tid * 16);
    }
    {
      int cb = acb ^ ((arow0 & 3) << 4);
      gload_lds16(W + (size_t)(n0 + arow0) * K + k0 + (cb >> 1), Bs + tid * 16);
    }
  }

  for (int kt = 0; kt < NK; kt++) {
    if (kt + 1 < NK) { asm volatile("s_waitcnt vmcnt(3)" ::: "memory"); }
    else             { asm volatile("s_waitcnt vmcnt(0)" ::: "memory"); }
    __builtin_amdgcn_sched_barrier(0);
    __builtin_amdgcn_s_barrier();
    __builtin_amdgcn_sched_barrier(0);

    const char* As = lds + (kt % 3) * SLOT_BYTES;
    const char* Bs = As + 16384;

    bf16x8 a[8], b[2];
#pragma unroll
    for (int mf = 0; mf < 8; mf++) {
      int row = wm * 128 + mf * 16 + fr;
      a[mf] = *(const bf16x8*)(As + row * 64 + (kqb ^ ((row & 3) << 4)));
    }
#pragma unroll
    for (int nf = 0; nf < 2; nf++) {
      int row = wn * 32 + nf * 16 + fr;
      b[nf] = *(const bf16x8*)(Bs + row * 64 + (kqb ^ ((row & 3) << 4)));
    }

    if (kt + 2 < NK) {
      char* Ad = lds + ((kt + 2) % 3) * SLOT_BYTES;
      char* Bd = Ad + 16384;
      const int k2 = (kt + 2) * 32;
#pragma unroll
      for (int i = 0; i < 2; i++) {
        int row = i * 128 + arow0;
        int cb = acb ^ ((row & 3) << 4);
        gload_lds16(A + (size_t)(m0 + row) * K + k2 + (cb >> 1), Ad + i * 8192 + tid * 16);
      }
      {
        int cb = acb ^ ((arow0 & 3) << 4);
        gload_lds16(W + (size_t)(n0 + arow0) * K + k2 + (cb >> 1), Bd + tid * 16);
      }
    }

    asm volatile("s_waitcnt lgkmcnt(0)" ::: "memory");
    __builtin_amdgcn_sched_barrier(0);
    __builtin_amdgcn_s_setprio(1);
#pragma unroll
    for (int mf = 0; mf < 8; mf++)
#pragma unroll
      for (int nf = 0; nf < 2; nf++)
        acc[mf][nf] = __builtin_amdgcn_mfma_f32_16x16x32_bf16(a[mf], b[nf], acc[mf][nf], 0, 0, 0);
    __builtin_amdgcn_s_setprio(0);
  }

  const int cr = lane & 15, rh = (lane >> 4) * 4;
#pragma unroll
  for (int nf = 0; nf < 2; nf++) {
    int n = n0 + wn * 32 + nf * 16 + cr;
    float bs = bias[n];
#pragma unroll
    for (int mf = 0; mf < 8; mf++) {
      int mb = m0 + wm * 128 + mf * 16 + rh;
#pragma unroll
      for (int r = 0; r < 4; r++) {
        float v = acc[mf][nf][r] + bs;
        if (ACT) v = fmaxf(v, 0.f);
        C[(size_t)(mb + r) * ldc + n] = f2b(v);
      }
    }
  }
}

// ---------------- fused t2 (512->256 relu) + final (256->1 sigmoid) ----------------
__global__ __launch_bounds__(256) void t2final_kernel(
    const ushort* __restrict__ A, const ushort* __restrict__ W,
    const float* __restrict__ bias, const float* __restrict__ w3,
    const float* __restrict__ b3, float* __restrict__ out) {
  __shared__ char smem[64 * 264 * 2];        // 33.8 KB; As/Bs overlay in front
  ushort* As = (ushort*)smem;                // 64 x 32 (4 KB)
  ushort* Bs = (ushort*)(smem + 4096);       // 256 x 32 (16 KB)
  ushort* Ct = (ushort*)smem;                // 64 x 264 after compute
  const int tid = threadIdx.x;
  const int lane = tid & 63, wave = tid >> 6;
  const int m0 = blockIdx.x * 64;

  const int srow = lane >> 2;
  const int scolb = ((lane & 3) << 4) ^ ((srow & 3) << 4);
  const ushort* Ag = A + (size_t)(m0 + wave * 16 + srow) * 512 + (scolb >> 1);
  const ushort* Wg = W + (size_t)(wave * 16 + srow) * 512 + (scolb >> 1);

  f32x4 acc[4][4] = {};
  const int fr = lane & 15;
  const int fkb = (lane >> 4) * 16;
  const int fswz = (fr & 3) << 4;

  for (int k0 = 0; k0 < 512; k0 += 32) {
    gload_lds16(Ag + k0, (char*)As + wave * 1024);
#pragma unroll
    for (int i = 0; i < 4; i++)
      gload_lds16(Wg + (size_t)(i * 64) * 512 + k0, (char*)Bs + i * 4096 + wave * 1024);
    __syncthreads();
    bf16x8 a[4], b[4];
#pragma unroll
    for (int i = 0; i < 4; i++) {
      a[i] = *(const bf16x8*)((const char*)As + (i * 16 + fr) * 64 + (fkb ^ fswz));
      b[i] = *(const bf16x8*)((const char*)Bs + (wave * 64 + i * 16 + fr) * 64 + (fkb ^ fswz));
    }
#pragma unroll
    for (int i = 0; i < 4; i++)
#pragma unroll
      for (int j = 0; j < 4; j++)
        acc[i][j] = __builtin_amdgcn_mfma_f32_16x16x32_bf16(a[i], b[j], acc[i][j], 0, 0, 0);
    __syncthreads();
  }

  const int col_l = lane & 15, row_h = (lane >> 4) * 4;
#pragma unroll
  for (int j = 0; j < 4; j++) {
    int n = wave * 64 + j * 16 + col_l;
    float bs = bias[n];
#pragma unroll
    for (int i = 0; i < 4; i++) {
      int mb = i * 16 + row_h;
#pragma unroll
      for (int r = 0; r < 4; r++)
        Ct[(size_t)(mb + r) * 264 + n] = f2b(fmaxf(acc[i][j][r] + bs, 0.f));
    }
  }
  __syncthreads();

  const float4 wv = ((const float4*)w3)[lane];
  const float bf = b3[0];
  for (int rr = 0; rr < 16; rr++) {
    int row = wave * 16 + rr;
    ushort4 a4 = *(const ushort4*)&Ct[(size_t)row * 264 + lane * 4];
    float s = b2f(a4.x) * wv.x + b2f(a4.y) * wv.y + b2f(a4.z) * wv.z + b2f(a4.w) * wv.w;
#pragma unroll
    for (int off = 32; off >= 1; off >>= 1) s += __shfl_xor(s, off);
    if (lane == 0) out[m0 + row] = 1.f / (1.f + expf(-(s + bf)));
  }
}

extern "C" void kernel_launch(void* const* d_in, const int* in_sizes, int n_in,
                              void* d_out, int out_size, void* d_ws, size_t ws_size,
                              hipStream_t stream) {
  const float* dense_x = (const float*)d_in[0];
  const int* lS_i = (const int*)d_in[2];
  const float* emb = (const float*)d_in[3];
  const float* bw0 = (const float*)d_in[4];
  const float* bb0 = (const float*)d_in[5];
  const float* bw1 = (const float*)d_in[6];
  const float* bb1 = (const float*)d_in[7];
  const float* bw2 = (const float*)d_in[8];
  const float* bb2 = (const float*)d_in[9];
  const float* tw0 = (const float*)d_in[10];
  const float* tb0 = (const float*)d_in[11];
  const float* tw1 = (const float*)d_in[12];
  const float* tb1 = (const float*)d_in[13];
  const float* tw2 = (const float*)d_in[14];
  const float* tb2 = (const float*)d_in[15];
  const float* tw3 = (const float*)d_in[16];
  const float* tb3 = (const float*)d_in[17];
  float* out = (float*)d_out;

  // workspace layout (bf16)
  char* w = (char*)d_ws;
  ushort* xb  = (ushort*)w; w += (size_t)BATCH * 128 * 2;
  ushort* x1  = (ushort*)w; w += (size_t)BATCH * 512 * 2;   // reused as t2
  ushort* x2  = (ushort*)w; w += (size_t)BATCH * 256 * 2;   // unused
  ushort* R   = (ushort*)w; w += (size_t)BATCH * 512 * 2;
  ushort* t1  = (ushort*)w; w += (size_t)BATCH * 1024 * 2;
  ushort* wb1 = (ushort*)w; w += 256 * 512 * 2;
  ushort* wb2 = (ushort*)w; w += 128 * 256 * 2;
  ushort* wt0 = (ushort*)w; w += 1024 * 512 * 2;
  ushort* wt1 = (ushort*)w; w += 512 * 1024 * 2;
  ushort* wt2 = (ushort*)w; w += 256 * 512 * 2;
  ushort* dxp = (ushort*)w; w += (size_t)BATCH * 32 * 2;
  ushort* wb0 = (ushort*)w; w += 512 * 32 * 2;
  ushort* t2 = x1;
  (void)x2;

  // prep: all conversions + dense_x pad (one launch)
  prep_kernel<<<dim3(2048, 7), 256, 0, stream>>>(
      dense_x, bw0, bw1, bw2, tw0, tw1, tw2, dxp, wb0,
      wb1, wb2, wt0, wt1, wt2);

  // fused bottom MLP 13->512->256->128 -> xb (packed B x 128)
  bmlp_kernel<<<BATCH / 64, 256, 0, stream>>>(dxp, wb0, bb0, wb1, bb1, wb2, bb2, xb);

  // fused embeddings + interaction -> R = [x | tril(Z) | 0pad]
  embint_kernel<<<BATCH / 4, 256, 0, stream>>>(emb, lS_i, xb, R);

  // top MLP
  gemm256_kernel<1><<<dim3(1024 / 128, BATCH / 256), 512, 0, stream>>>(R,  wt0, tb0, t1, 512, 1024);
  gemm256_kernel<1><<<dim3(512 / 128,  BATCH / 256), 512, 0, stream>>>(t1, wt1, tb1, t2, 1024, 512);
  t2final_kernel<<<BATCH / 64, 256, 0, stream>>>(t2, wt2, tb2, tw3, tb3, out);
}